// Round 9
// baseline (510.153 us; speedup 1.0000x reference)
//
#include <hip/hip_runtime.h>
#include <hip/hip_bf16.h>
#include <math.h>

#define B_SZ 2
#define L_SZ 2048
#define DMODEL 1024
#define DINNER 2048
#define DSTATE 16
#define DTRANK 64
#define M_ROWS (B_SZ * L_SZ)   // 4096

#define CH 32
#define CLEN (L_SZ / CH)
#define CPB 64

#define KSPLIT 8
#define KC (DINNER / KSPLIT)   // 256

typedef short shortx8 __attribute__((ext_vector_type(8)));
typedef float floatx4 __attribute__((ext_vector_type(4)));
typedef float floatx16 __attribute__((ext_vector_type(16)));

__device__ __forceinline__ float softplusf(float x) {
    return fmaxf(x, 0.f) + log1pf(expf(-fabsf(x)));
}
__device__ __forceinline__ float siluf(float x) {
    return x * (1.f / (1.f + expf(-x)));
}

__device__ __forceinline__ void async_ld16(const void* g, void* l) {
    __builtin_amdgcn_global_load_lds(
        (__attribute__((address_space(1))) void*)(unsigned long long)g,
        (__attribute__((address_space(3))) void*)(unsigned int)(unsigned long long)l,
        16, 0, 0);
}

// ---------------------------------------------------------------------------
// R18: (a) REVERT gemm_8ph to the R16-exact phase structure (R8's bunched
// reads regressed 92.8->97.9us, falsifier fired -> 92.8 is this skeleton's
// floor; two schedule experiments null/negative). (b) xproj_splitk BK 16->64:
// R3's throttled-box data showed mid-kernels here are LATENCY-bound (old
// dtproj: 133us @ 3.6% HBM, 21% VALU -- barrier-round serialization), and
// xproj had 16 k0-rounds x 2 barriers = 32 serialized stage+barrier
// latencies. BK=64 -> 4 rounds, LDS 42KB -> 3 blocks/CU, staging pattern
// identical to the proven dtproj kernel.
// ---------------------------------------------------------------------------

// fp32 [ROWS][KSRC] -> dedup 2-seg ([h|l]) panelized bf16 in LDS-image order.
template <int ROWS, int KSRC>
__global__ __launch_bounds__(256) void split3_kernel(
    const float* __restrict__ src, unsigned short* __restrict__ dst)
{
    constexpr int SEGT = KSRC / 64;
    int i = blockIdx.x * 256 + threadIdx.x;   // ROWS x (KSRC/8) k8-groups
    int row = i & (ROWS - 1);
    int k8s = i / ROWS;
    const float* s = src + (size_t)row * KSRC + k8s * 8;
    float4 v0 = *(const float4*)s;
    float4 v1 = *(const float4*)(s + 4);
    float vs[8] = {v0.x, v0.y, v0.z, v0.w, v1.x, v1.y, v1.z, v1.w};
    unsigned short hsv[8], lsv[8];
#pragma unroll
    for (int j = 0; j < 8; ++j) {
        __hip_bfloat16 h = __float2bfloat16(vs[j]);
        __hip_bfloat16 l = __float2bfloat16(vs[j] - __bfloat162float(h));
        hsv[j] = *(unsigned short*)&h;
        lsv[j] = *(unsigned short*)&l;
    }
    int tloc = k8s >> 3;
    int sh = (k8s >> 2) & 1;
    int k8l = k8s & 3;
    size_t off = ((size_t)(row >> 8) * 4 * SEGT + tloc * 2 + sh) * 8192
               + (size_t)(k8l * 256 + (row & 255)) * 8;
    *(shortx8*)&dst[off] = *(shortx8*)hsv;
    *(shortx8*)&dst[off + (size_t)2 * SEGT * 8192] = *(shortx8*)lsv;
}

// ---------------------------------------------------------------------------
// 8-phase 256x256 pipelined bf16 GEMM over dedup-2-seg panels (R14/R16
// schedule -- verified 92.6-92.8us @ 47% MfmaUtil across 4 rounds/3 boxes).
// KT = K-tiles (even); SEGT = tiles per segment; NB = n-blocks.
// Grid = (M/256)*NB = 256 blocks, 512 threads.
// ---------------------------------------------------------------------------
template <int KT, int SEGT, int NB, int LDC>
__global__ __launch_bounds__(512, 2) void gemm_8ph(
    const unsigned short* __restrict__ Ap,
    const unsigned short* __restrict__ Bp,
    float* __restrict__ C)
{
    __shared__ unsigned short lds[65536];   // 128KB: [slot][A|B][kh][k8l*256+row]*8

    const int tid = threadIdx.x;
    const int lane = tid & 63;
    const int w = tid >> 6;                 // 0..7
    const int wm = w >> 2, wn = w & 3;      // 2 x 4
    const int l15 = lane & 15, l4 = lane >> 4;

    int id = blockIdx.x;
    id = (id & 7) * 32 + (id >> 3);         // bijective XCD swizzle (256 blocks)
    const int bm = id / NB;
    const int bn = id % NB;

    const unsigned short* ga = Ap + (size_t)bm * 4 * SEGT * 8192;
    const unsigned short* gb = Bp + (size_t)bn * 4 * SEGT * 8192;

    const int rA = (l4 * 256 + wm * 128 + l15) * 8;
    const int rB = (l4 * 256 + wn * 64 + l15) * 8;

    floatx4 acc[8][4] = {};
    shortx8 bfr[4];

    // stage one 16KB region: slot=(vt&1), ab in {0=A,1=B}, s = k-half
    auto STAGE = [&](int vt, int ab, int s) {
        int Tv = vt < KT ? vt : KT - 1;    // virtual tiles clamp (counts stay exact)
        int Tm = ab ? (Tv >= SEGT ? Tv - SEGT : Tv)            // B: [h,h,l]
                    : (Tv >= 2 * SEGT ? Tv - 2 * SEGT : Tv);   // A: [h,l,h]
        const unsigned short* src = (ab ? gb : ga) + ((size_t)Tm * 2 + s) * 8192 + tid * 8;
        unsigned short* dst = (unsigned short*)lds + (vt & 1) * 32768 + ab * 16384 + s * 8192 + tid * 8;
        async_ld16(src, dst);
        async_ld16(src + 4096, dst + 4096);
    };

#define MFMA16(MH)                                                                             \
    acc[(MH)*4+0][0] = __builtin_amdgcn_mfma_f32_16x16x32_bf16(af0, bfr[0], acc[(MH)*4+0][0], 0,0,0); \
    acc[(MH)*4+0][1] = __builtin_amdgcn_mfma_f32_16x16x32_bf16(af0, bfr[1], acc[(MH)*4+0][1], 0,0,0); \
    acc[(MH)*4+0][2] = __builtin_amdgcn_mfma_f32_16x16x32_bf16(af0, bfr[2], acc[(MH)*4+0][2], 0,0,0); \
    acc[(MH)*4+0][3] = __builtin_amdgcn_mfma_f32_16x16x32_bf16(af0, bfr[3], acc[(MH)*4+0][3], 0,0,0); \
    acc[(MH)*4+1][0] = __builtin_amdgcn_mfma_f32_16x16x32_bf16(af1, bfr[0], acc[(MH)*4+1][0], 0,0,0); \
    acc[(MH)*4+1][1] = __builtin_amdgcn_mfma_f32_16x16x32_bf16(af1, bfr[1], acc[(MH)*4+1][1], 0,0,0); \
    acc[(MH)*4+1][2] = __builtin_amdgcn_mfma_f32_16x16x32_bf16(af1, bfr[2], acc[(MH)*4+1][2], 0,0,0); \
    acc[(MH)*4+1][3] = __builtin_amdgcn_mfma_f32_16x16x32_bf16(af1, bfr[3], acc[(MH)*4+1][3], 0,0,0); \
    acc[(MH)*4+2][0] = __builtin_amdgcn_mfma_f32_16x16x32_bf16(af2, bfr[0], acc[(MH)*4+2][0], 0,0,0); \
    acc[(MH)*4+2][1] = __builtin_amdgcn_mfma_f32_16x16x32_bf16(af2, bfr[1], acc[(MH)*4+2][1], 0,0,0); \
    acc[(MH)*4+2][2] = __builtin_amdgcn_mfma_f32_16x16x32_bf16(af2, bfr[2], acc[(MH)*4+2][2], 0,0,0); \
    acc[(MH)*4+2][3] = __builtin_amdgcn_mfma_f32_16x16x32_bf16(af2, bfr[3], acc[(MH)*4+2][3], 0,0,0); \
    acc[(MH)*4+3][0] = __builtin_amdgcn_mfma_f32_16x16x32_bf16(af3, bfr[0], acc[(MH)*4+3][0], 0,0,0); \
    acc[(MH)*4+3][1] = __builtin_amdgcn_mfma_f32_16x16x32_bf16(af3, bfr[1], acc[(MH)*4+3][1], 0,0,0); \
    acc[(MH)*4+3][2] = __builtin_amdgcn_mfma_f32_16x16x32_bf16(af3, bfr[2], acc[(MH)*4+3][2], 0,0,0); \
    acc[(MH)*4+3][3] = __builtin_amdgcn_mfma_f32_16x16x32_bf16(af3, bfr[3], acc[(MH)*4+3][3], 0,0,0);

// VM: 1 = counted s_waitcnt vmcnt(4) (phases 4 and 8 only; never 0 mid-loop)
#define PHASE(SLOT, S, MH, SVT, SAB, SS, VM)                                   \
    {                                                                          \
        const unsigned short* Ab = &lds[(SLOT)*32768 + (S)*8192] + rA;         \
        shortx8 af0 = *(const shortx8*)&Ab[((MH)*4 + 0) * 128];                \
        shortx8 af1 = *(const shortx8*)&Ab[((MH)*4 + 1) * 128];                \
        shortx8 af2 = *(const shortx8*)&Ab[((MH)*4 + 2) * 128];                \
        shortx8 af3 = *(const shortx8*)&Ab[((MH)*4 + 3) * 128];                \
        if ((MH) == 0) {                                                       \
            const unsigned short* Bb = &lds[(SLOT)*32768 + 16384 + (S)*8192] + rB; \
            bfr[0] = *(const shortx8*)&Bb[0];                                  \
            bfr[1] = *(const shortx8*)&Bb[128];                                \
            bfr[2] = *(const shortx8*)&Bb[256];                                \
            bfr[3] = *(const shortx8*)&Bb[384];                                \
        }                                                                      \
        STAGE(SVT, SAB, SS);                                                   \
        __builtin_amdgcn_s_barrier();                                          \
        asm volatile("s_waitcnt lgkmcnt(0)" ::: "memory");                     \
        __builtin_amdgcn_s_setprio(1);                                         \
        MFMA16(MH)                                                             \
        __builtin_amdgcn_s_setprio(0);                                         \
        if (VM) { asm volatile("s_waitcnt vmcnt(4)" ::: "memory"); }           \
        __builtin_amdgcn_s_barrier();                                          \
    }

    // prologue: t0 all 4 regions + t1 first 2, in consumption order.
    STAGE(0, 0, 0); STAGE(0, 1, 0); STAGE(0, 0, 1); STAGE(0, 1, 1);
    STAGE(1, 0, 0); STAGE(1, 1, 0);
    asm volatile("s_waitcnt vmcnt(4)" ::: "memory");
    __builtin_amdgcn_s_barrier();

#pragma unroll 1
    for (int i = 0; i < KT / 2; ++i) {
        const int t2 = 2 * i;
        PHASE(0, 0, 0, t2 + 1, 0, 1, 0)
        PHASE(0, 0, 1, t2 + 1, 1, 1, 0)
        PHASE(0, 1, 0, t2 + 2, 0, 0, 0)
        PHASE(0, 1, 1, t2 + 2, 1, 0, 1)   // vmcnt(4): all of t(2i+1) landed
        PHASE(1, 0, 0, t2 + 2, 0, 1, 0)
        PHASE(1, 0, 1, t2 + 2, 1, 1, 0)
        PHASE(1, 1, 0, t2 + 3, 0, 0, 0)
        PHASE(1, 1, 1, t2 + 3, 1, 0, 1)   // vmcnt(4): all of t(2i+2) landed
    }

#undef PHASE
#undef MFMA16

    // epilogue: C/D 16x16: col = lane&15, row = (lane>>4)*4 + reg (m89)
    const int c0 = bn * 256 + wn * 64;
    const int r0 = bm * 256 + wm * 128;
#pragma unroll
    for (int fi = 0; fi < 8; ++fi) {
#pragma unroll
        for (int fj = 0; fj < 4; ++fj) {
            int col = c0 + fj * 16 + l15;
            int rowb = r0 + fi * 16 + l4 * 4;
#pragma unroll
            for (int ri = 0; ri < 4; ++ri)
                C[(size_t)(rowb + ri) * LDC + col] = acc[fi][fj][ri];
        }
    }
}

// ---------------------------------------------------------------------------
// bf16 MFMA GEMM (R8 structure) -- out_proj.
// ---------------------------------------------------------------------------
template <int BN, int KP>
__global__ __launch_bounds__(256) void gemm_bf16_nt(
    const unsigned short* __restrict__ A,
    const unsigned short* __restrict__ Bm,
    float* __restrict__ C, int ldc)
{
    constexpr int TN32 = BN / 64;                 // 32-wide n-tiles per wave
    __shared__ unsigned short As[2 * 8192];       // [seg][t][128 rows][32 k]
    __shared__ unsigned short Bs[2 * BN * 64];    // [seg][t][BN rows][32 k]

    const int tid = threadIdx.x;
    const int w = tid >> 6;
    const int lane = tid & 63;
    const int wm = w >> 1, wn = w & 1;
    const int m0 = blockIdx.y * 128;
    const int n0 = blockIdx.x * BN;

    const int r4 = lane >> 2;                        // staging row in 16-group
    const int csw = (lane & 3) ^ ((r4 >> 1) & 3);    // swizzled source chunk
    const int gk = csw * 8;                          // shorts offset
    const int l31 = lane & 31;
    const int khalf = lane >> 5;                     // 0/1: k-half within 16
    const int rsw = (l31 >> 1) & 3;                  // read-side swizzle key

    floatx16 acc[2][TN32] = {};

    for (int k0 = 0; k0 < KP; k0 += 64) {
#pragma unroll
        for (int seg = 0; seg < 2; ++seg) {
            const unsigned short* Asrc = A + seg * KP;
            const unsigned short* Bsrc = Bm + seg * KP;
#pragma unroll
            for (int t = 0; t < 2; ++t) {
#pragma unroll
                for (int jj = 0; jj < 2; ++jj) {
                    int j = w + jj * 4;
                    async_ld16(Asrc + (size_t)(m0 + j * 16 + r4) * (2 * KP) + k0 + t * 32 + gk,
                               &As[seg * 8192 + t * 4096 + j * 512]);
                }
#pragma unroll
                for (int jj = 0; jj < BN / 64; ++jj) {
                    int j = w + jj * 4;
                    async_ld16(Bsrc + (size_t)(n0 + j * 16 + r4) * (2 * KP) + k0 + t * 32 + gk,
                               &Bs[seg * BN * 64 + t * BN * 32 + j * 512]);
                }
            }
        }
        __syncthreads();

#pragma unroll
        for (int t = 0; t < 2; ++t) {
#pragma unroll
            for (int kk = 0; kk < 2; ++kk) {
                const int pos = ((kk * 2 + khalf) ^ rsw) << 3;
                shortx8 ah[2], al[2], bh[TN32], bl[TN32];
#pragma unroll
                for (int i = 0; i < 2; ++i) {
                    int row = wm * 64 + i * 32 + l31;
                    ah[i] = *(const shortx8*)&As[t * 4096 + row * 32 + pos];
                    al[i] = *(const shortx8*)&As[8192 + t * 4096 + row * 32 + pos];
                }
#pragma unroll
                for (int j = 0; j < TN32; ++j) {
                    int col = wn * (BN / 2) + j * 32 + l31;
                    bh[j] = *(const shortx8*)&Bs[t * BN * 32 + col * 32 + pos];
                    bl[j] = *(const shortx8*)&Bs[BN * 64 + t * BN * 32 + col * 32 + pos];
                }
#pragma unroll
                for (int i = 0; i < 2; ++i)
#pragma unroll
                    for (int j = 0; j < TN32; ++j) {
                        acc[i][j] = __builtin_amdgcn_mfma_f32_32x32x16_bf16(ah[i], bh[j], acc[i][j], 0, 0, 0);
                        acc[i][j] = __builtin_amdgcn_mfma_f32_32x32x16_bf16(ah[i], bl[j], acc[i][j], 0, 0, 0);
                        acc[i][j] = __builtin_amdgcn_mfma_f32_32x32x16_bf16(al[i], bh[j], acc[i][j], 0, 0, 0);
                    }
            }
        }
        __syncthreads();
    }

#pragma unroll
    for (int i = 0; i < 2; ++i) {
#pragma unroll
        for (int j = 0; j < TN32; ++j) {
            int col = n0 + wn * (BN / 2) + j * 32 + l31;
#pragma unroll
            for (int r = 0; r < 16; ++r) {
                int row = m0 + wm * 64 + i * 32 + (r & 3) + 8 * (r >> 2) + 4 * khalf;
                C[(size_t)row * ldc + col] = acc[i][j][r];
            }
        }
    }
}

// ---------------------------------------------------------------------------
// fp32 -> 2-segment split-bf16: row = [hi (K) | lo (K)], stride 2K (out_proj)
// ---------------------------------------------------------------------------
__global__ __launch_bounds__(256) void split2_kernel(
    const float* __restrict__ src, unsigned short* __restrict__ dst, int K)
{
    int i = blockIdx.x * 256 + threadIdx.x;
    int m = i / K;
    int k = i - m * K;
    float a = src[i];
    __hip_bfloat16 h = __float2bfloat16(a);
    __hip_bfloat16 l = __float2bfloat16(a - __bfloat162float(h));
    unsigned short* row = dst + (size_t)m * 2 * K;
    row[k] = *(unsigned short*)&h;
    row[K + k] = *(unsigned short*)&l;
}

// ---------------------------------------------------------------------------
// x_proj split-K partial GEMM + reduce. R18: BK=64 (4 k0-rounds per block
// instead of 16 -- barrier-round latency was the binder, cf. R3 dtproj).
// LDS 42KB -> 3 blocks/CU. Staging pattern identical to dtproj (proven).
// ---------------------------------------------------------------------------
__global__ __launch_bounds__(256) void xproj_splitk(
    const float* __restrict__ u, const float* __restrict__ Wx,
    float* __restrict__ Cp)
{
    __shared__ float As[64][68];     // [k][row]
    __shared__ float Bs[64][100];    // [k][row]

    const int tid = threadIdx.x;
    const int ks = blockIdx.x;
    const int m0 = blockIdx.y * 64;
    const int tx = tid & 15;
    const int ty = tid >> 4;

    float acc[4][6] = {};

    for (int k0 = ks * KC; k0 < (ks + 1) * KC; k0 += 64) {
        // stage A: 64 rows x 64 k (k-major), 4 float4 rounds
        for (int idx = tid * 4; idx < 64 * 64; idx += 1024) {
            int row = idx >> 6, kk = idx & 63;
            float4 v = *(const float4*)&u[(size_t)(m0 + row) * DINNER + k0 + kk];
            As[kk + 0][row] = v.x;
            As[kk + 1][row] = v.y;
            As[kk + 2][row] = v.z;
            As[kk + 3][row] = v.w;
        }
        // stage B: 96 rows x 64 k, 6 float4 rounds
        for (int idx = tid * 4; idx < 96 * 64; idx += 1024) {
            int row = idx >> 6, kk = idx & 63;
            float4 v = *(const float4*)&Wx[(size_t)row * DINNER + k0 + kk];
            Bs[kk + 0][row] = v.x;
            Bs[kk + 1][row] = v.y;
            Bs[kk + 2][row] = v.z;
            Bs[kk + 3][row] = v.w;
        }
        __syncthreads();

#pragma unroll 8
        for (int k = 0; k < 64; ++k) {
            float a[4], b[6];
#pragma unroll
            for (int i = 0; i < 4; ++i) a[i] = As[k][ty * 4 + i];
#pragma unroll
            for (int j = 0; j < 6; ++j) b[j] = Bs[k][tx * 6 + j];
#pragma unroll
            for (int i = 0; i < 4; ++i)
#pragma unroll
                for (int j = 0; j < 6; ++j) acc[i][j] = fmaf(a[i], b[j], acc[i][j]);
        }
        __syncthreads();
    }

    float* outp = Cp + ((size_t)ks * M_ROWS + m0) * 96;
#pragma unroll
    for (int i = 0; i < 4; ++i)
#pragma unroll
        for (int j = 0; j < 6; ++j)
            outp[(ty * 4 + i) * 96 + tx * 6 + j] = acc[i][j];
}

__global__ __launch_bounds__(256) void xproj_reduce(
    const float* __restrict__ Cp, float* __restrict__ xdbl)
{
    int i = blockIdx.x * 256 + threadIdx.x;
    float s = 0.f;
#pragma unroll
    for (int c = 0; c < KSPLIT; ++c)
        s += Cp[(size_t)c * M_ROWS * 96 + i];
    xdbl[i] = s;
}

// ---------------------------------------------------------------------------
// dt_proj + softplus, K=64 staged once. Tile 64(M) x 128(N), TM4 x TN8.
// ---------------------------------------------------------------------------
__global__ __launch_bounds__(256) void dtproj_kernel(
    const float* __restrict__ A, const float* __restrict__ Bw,
    const float* __restrict__ bias, float* __restrict__ Cout)
{
    __shared__ float As[64][68];
    __shared__ float Bs[64][132];

    const int tid = threadIdx.x;
    const int m0 = blockIdx.y * 64;
    const int n0 = blockIdx.x * 128;
    const int tx = tid & 15;
    const int ty = tid >> 4;

    for (int idx = tid * 4; idx < 64 * 64; idx += 1024) {
        int row = idx >> 6, kk = idx & 63;
        float4 v = *(const float4*)&A[(size_t)(m0 + row) * 96 + kk];
        As[kk + 0][row] = v.x;
        As[kk + 1][row] = v.y;
        As[kk + 2][row] = v.z;
        As[kk + 3][row] = v.w;
    }
    for (int idx = tid * 4; idx < 128 * 64; idx += 1024) {
        int row = idx >> 6, kk = idx & 63;
        float4 v = *(const float4*)&Bw[(size_t)(n0 + row) * 64 + kk];
        Bs[kk + 0][row] = v.x;
        Bs[kk + 1][row] = v.y;
        Bs[kk + 2][row] = v.z;
        Bs[kk + 3][row] = v.w;
    }
    __syncthreads();

    float acc[4][8] = {};
#pragma unroll 8
    for (int k = 0; k < 64; ++k) {
        float a[4], b[8];
        *(float4*)a = *(const float4*)&As[k][ty * 4];
        *(float4*)&b[0] = *(const float4*)&Bs[k][tx * 8];
        *(float4*)&b[4] = *(const float4*)&Bs[k][tx * 8 + 4];
#pragma unroll
        for (int i = 0; i < 4; ++i)
#pragma unroll
            for (int j = 0; j < 8; ++j) acc[i][j] = fmaf(a[i], b[j], acc[i][j]);
    }

#pragma unroll
    for (int i = 0; i < 4; ++i) {
        int m = m0 + ty * 4 + i;
        float o[8];
#pragma unroll
        for (int j = 0; j < 8; ++j)
            o[j] = softplusf(acc[i][j] + bias[n0 + tx * 8 + j]);
        float* dst = &Cout[(size_t)m * DINNER + n0 + tx * 8];
        *(float4*)&dst[0] = *(float4*)&o[0];
        *(float4*)&dst[4] = *(float4*)&o[4];
    }
}

// ---------------------------------------------------------------------------
// conv + silu, float4 over channels
// ---------------------------------------------------------------------------
__global__ __launch_bounds__(256) void conv_silu_v4(
    const float* __restrict__ xz, const float* __restrict__ cw,
    const float* __restrict__ cb, float* __restrict__ u)
{
    int i = blockIdx.x * 256 + threadIdx.x;      // over M_ROWS * 512
    int dq = (i & 511) << 2;
    int bl = i >> 9;
    int b = bl >> 11;
    int l = bl & 2047;

    float4 W0 = *(const float4*)&cw[(dq + 0) * 4];
    float4 W1 = *(const float4*)&cw[(dq + 1) * 4];
    float4 W2 = *(const float4*)&cw[(dq + 2) * 4];
    float4 W3 = *(const float4*)&cw[(dq + 3) * 4];
    float4 acc = *(const float4*)&cb[dq];

#pragma unroll
    for (int k = 0; k < 4; ++k) {
        int ls = l + k - 3;
        if (ls >= 0) {
            float4 v = *(const float4*)&xz[((size_t)(b << 11) + ls) * 4096 + dq];
            acc.x = fmaf(v.x, ((const float*)&W0)[k], acc.x);
            acc.y = fmaf(v.y, ((const float*)&W1)[k], acc.y);
            acc.z = fmaf(v.z, ((const float*)&W2)[k], acc.z);
            acc.w = fmaf(v.w, ((const float*)&W3)[k], acc.w);
        }
    }
    float4 r = make_float4(siluf(acc.x), siluf(acc.y), siluf(acc.z), siluf(acc.w));
    *(float4*)&u[(size_t)bl * DINNER + dq] = r;
}

// ---------------------------------------------------------------------------
// Chunked selective scan (3 passes). PASS3 fuses gate + split-bf16 y2
// (linear 2-seg layout [4096][hi 2048 | lo 2048]).
// ---------------------------------------------------------------------------
template <bool PASS3>
__global__ __launch_bounds__(256) void scan_chunk(
    const float* __restrict__ dbuf, const float* __restrict__ ubuf,
    const float* __restrict__ xdbl, const float* __restrict__ A_log,
    const float* __restrict__ Dv,
    float* __restrict__ Pbuf, float* __restrict__ Sbuf,
    const float* __restrict__ xz, unsigned short* __restrict__ y2)
{
    __shared__ float sd[16][CPB];
    __shared__ float su[16][CPB];
    __shared__ float sB[16][DSTATE];
    __shared__ float sC[16][DSTATE];

    const int tid = threadIdx.x;
    const int c    = blockIdx.x % CH;
    const int dblk = (blockIdx.x / CH) % (DINNER / CPB);
    const int b    = blockIdx.x / (CH * (DINNER / CPB));
    const int d0 = dblk * CPB;
    const int dg = tid >> 2;
    const int q  = tid & 3;
    const int d  = d0 + dg;
    const size_t base_bl = (size_t)b * L_SZ + (size_t)c * CLEN;

    float Ac[4], h[4];
    float sdl = 0.f;
#pragma unroll
    for (int j = 0; j < 4; ++j)
        Ac[j] = -expf(A_log[d * DSTATE + 4 * q + j]);
    const size_t psoff = (((size_t)b * CH + c) * DINNER + d0) * DSTATE + (size_t)tid * 4;
    if (PASS3) {
        float4 h0 = *(const float4*)&Sbuf[psoff];
        h[0] = h0.x; h[1] = h0.y; h[2] = h0.z; h[3] = h0.w;
    } else {
        h[0] = h[1] = h[2] = h[3] = 0.f;
    }
    const float Dd = PASS3 ? Dv[d] : 0.f;

    const int ls = tid >> 4;
    const int g4 = (tid & 15) * 4;
    const int ln = tid & 15;

    float4 r_d = *(const float4*)&dbuf[(base_bl + ls) * DINNER + d0 + g4];
    float4 r_u = *(const float4*)&ubuf[(base_bl + ls) * DINNER + d0 + g4];
    float r_B = xdbl[(base_bl + ls) * 96 + 64 + ln];
    float r_C = xdbl[(base_bl + ls) * 96 + 80 + ln];

    for (int l0 = 0; l0 < CLEN; l0 += 16) {
        __syncthreads();
        *(float4*)&sd[ls][g4] = r_d;
        *(float4*)&su[ls][g4] = r_u;
        sB[ls][ln] = r_B;
        sC[ls][ln] = r_C;
        __syncthreads();

        if (l0 + 16 < CLEN) {
            r_d = *(const float4*)&dbuf[(base_bl + l0 + 16 + ls) * DINNER + d0 + g4];
            r_u = *(const float4*)&ubuf[(base_bl + l0 + 16 + ls) * DINNER + d0 + g4];
            r_B = xdbl[(base_bl + l0 + 16 + ls) * 96 + 64 + ln];
            r_C = xdbl[(base_bl + l0 + 16 + ls) * 96 + 80 + ln];
        }

#pragma unroll
        for (int s = 0; s < 16; ++s) {
            float dl = sd[s][dg];
            float ul = su[s][dg];
            float4 Bv = *(float4*)&sB[s][4 * q];
            float dbu = dl * ul;
            float dA0 = expf(dl * Ac[0]);
            float dA1 = expf(dl * Ac[1]);
            float dA2 = expf(dl * Ac[2]);
            float dA3 = expf(dl * Ac[3]);
            h[0] = fmaf(dA0, h[0], dbu * Bv.x);
            h[1] = fmaf(dA1, h[1], dbu * Bv.y);
            h[2] = fmaf(dA2, h[2], dbu * Bv.z);
            h[3] = fmaf(dA3, h[3], dbu * Bv.w);
            if (!PASS3) {
                sdl += dl;
            } else {
                float4 Cv = *(float4*)&sC[s][4 * q];
                float y = h[0] * Cv.x + h[1] * Cv.y + h[2] * Cv.z + h[3] * Cv.w;
                y += __shfl_xor(y, 1);
                y += __shfl_xor(y, 2);
                if (q == 0) su[s][dg] = fmaf(ul, Dd, y);
            }
        }

        if (PASS3) {
            __syncthreads();
            size_t row = base_bl + l0 + ls;
            float4 yv = *(float4*)&su[ls][g4];
            float4 rv = *(const float4*)&xz[row * 4096 + 2048 + d0 + g4];
            float a0 = yv.x * siluf(rv.x);
            float a1 = yv.y * siluf(rv.y);
            float a2 = yv.z * siluf(rv.z);
            float a3 = yv.w * siluf(rv.w);
            __hip_bfloat16 h0 = __float2bfloat16(a0), h1 = __float2bfloat16(a1);
            __hip_bfloat16 h2 = __float2bfloat16(a2), h3 = __float2bfloat16(a3);
            __hip_bfloat16 l0b = __float2bfloat16(a0 - __bfloat162float(h0));
            __hip_bfloat16 l1b = __float2bfloat16(a1 - __bfloat162float(h1));
            __hip_bfloat16 l2b = __float2bfloat16(a2 - __bfloat162float(h2));
            __hip_bfloat16 l3b = __float2bfloat16(a3 - __bfloat162float(h3));
            ushort4 hv = make_ushort4(*(unsigned short*)&h0, *(unsigned short*)&h1,
                                      *(unsigned short*)&h2, *(unsigned short*)&h3);
            ushort4 lv = make_ushort4(*(unsigned short*)&l0b, *(unsigned short*)&l1b,
                                      *(unsigned short*)&l2b, *(unsigned short*)&l3b);
            unsigned short* yrow = y2 + row * 2 * DINNER + d0 + g4;
            *(ushort4*)&yrow[0] = hv;
            *(ushort4*)&yrow[DINNER] = lv;
        }
    }

    if (!PASS3) {
        *(float4*)&Pbuf[psoff] = make_float4(expf(Ac[0] * sdl), expf(Ac[1] * sdl),
                                             expf(Ac[2] * sdl), expf(Ac[3] * sdl));
        *(float4*)&Sbuf[psoff] = make_float4(h[0], h[1], h[2], h[3]);
    }
}

__global__ __launch_bounds__(256) void scan_combine(
    const float* __restrict__ Pbuf, float* __restrict__ Sbuf)
{
    int t = blockIdx.x * 256 + threadIdx.x;
    int b = t >> 15;
    int rem = t & 32767;
    size_t base = (size_t)b * CH * DINNER * DSTATE + rem;
    float H = 0.f;
#pragma unroll 4
    for (int c = 0; c < CH; ++c) {
        size_t off = base + (size_t)c * DINNER * DSTATE;
        float S = Sbuf[off];
        float P = Pbuf[off];
        Sbuf[off] = H;
        H = fmaf(P, H, S);
    }
}

// ---------------------------------------------------------------------------
extern "C" void kernel_launch(void* const* d_in, const int* in_sizes, int n_in,
                              void* d_out, int out_size, void* d_ws, size_t ws_size,
                              hipStream_t stream)
{
    const float* x          = (const float*)d_in[0];
    const float* in_proj_w  = (const float*)d_in[1];
    const float* conv_w     = (const float*)d_in[2];
    const float* conv_b     = (const float*)d_in[3];
    const float* x_proj_w   = (const float*)d_in[4];
    const float* dt_proj_w  = (const float*)d_in[5];
    const float* dt_proj_b  = (const float*)d_in[6];
    const float* A_log      = (const float*)d_in[7];
    const float* Dv         = (const float*)d_in[8];
    const float* out_proj_w = (const float*)d_in[9];
    float* out = (float*)d_out;

    // workspace layout (bytes):
    char* w = (char*)d_ws;
    float* xz   = (float*)(w);                       // 64 MB
    float* u    = (float*)(w + 67108864);            // 32 MB (written step 3)
    float* dbuf = (float*)(w + 100663296);           // 32 MB (written step 5)
    float* xdbl = (float*)(w + 134217728);           // 1.5 MB
    float* Pbuf = (float*)(w + 135790592);           // 8 MB (dead after combine)
    float* Sbuf = (float*)(w + 144179200);           // 8 MB (ends 152567808)
    unsigned short* y2  = (unsigned short*)(w + 152567808);   // 32 MB [4096][4096] 2-seg
    unsigned short* w2b = (unsigned short*)(w + 135790592);   // 8 MB over Pbuf (dead at 7)
    float* Cp = (float*)(w + 152567808);             // xproj partials (dead at 4, pre-y2)
    // dedup 2-seg panels for in_proj; ALIAS u / dbuf (dead after step 2)
    unsigned short* x2p  = (unsigned short*)(w + 67108864);   // 16 MB over u
    unsigned short* w2ap = (unsigned short*)(w + 100663296);  // 16 MB over dbuf

    // 1) split x / in_proj_w -> dedup 2-seg panels (K'=3072 traversal)
    split3_kernel<4096, 1024><<<2048, 256, 0, stream>>>(x, x2p);
    split3_kernel<4096, 1024><<<2048, 256, 0, stream>>>(in_proj_w, w2ap);
    // 2) in_proj: 8-phase GEMM, KT=48, SEGT=16, NB=16 (R16-exact, 92.8us)
    gemm_8ph<48, 16, 16, 4096><<<256, 512, 0, stream>>>(x2p, w2ap, xz);
    // 3) conv + silu -> u (overwrites x2p, dead)
    conv_silu_v4<<<(M_ROWS * 512) / 256, 256, 0, stream>>>(xz, conv_w, conv_b, u);
    // 4) x_proj via split-K (BK=64)
    {
        dim3 g(KSPLIT, M_ROWS / 64);
        xproj_splitk<<<g, 256, 0, stream>>>(u, x_proj_w, Cp);
        xproj_reduce<<<(M_ROWS * 96) / 256, 256, 0, stream>>>(Cp, xdbl);
    }
    // 5) dt_proj + softplus -> dbuf (overwrites w2ap, dead)
    {
        dim3 g(DINNER / 128, M_ROWS / 64);
        dtproj_kernel<<<g, 256, 0, stream>>>(xdbl, dt_proj_w, dt_proj_b, dbuf);
    }
    // 6) chunked selective scan; pass3 fuses gate + linear 2-seg split into y2
    {
        const int nblk = B_SZ * (DINNER / CPB) * CH;
        scan_chunk<false><<<nblk, 256, 0, stream>>>(dbuf, u, xdbl, A_log, Dv, Pbuf, Sbuf, nullptr, nullptr);
        scan_combine<<<B_SZ * DINNER * DSTATE / 256, 256, 0, stream>>>(Pbuf, Sbuf);
        scan_chunk<true><<<nblk, 256, 0, stream>>>(dbuf, u, xdbl, A_log, Dv, nullptr, Sbuf, xz, y2);
    }
    // 7) split out_proj_w (2-seg linear; Pbuf dead after combine)
    split2_kernel<<<(DMODEL * DINNER) / 256, 256, 0, stream>>>(out_proj_w, w2b, DINNER);
    // 8) out_proj via 32x32x16 MFMA (R8 structure)
    {
        dim3 g(1024 / 64, M_ROWS / 128);
        gemm_bf16_nt<64, 2048><<<g, 256, 0, stream>>>(y2, w2b, out, 1024);
    }
}

// Round 10
// 510.024 us; speedup vs baseline: 1.0003x; 1.0003x over previous
//
#include <hip/hip_runtime.h>
#include <hip/hip_bf16.h>
#include <math.h>

#define B_SZ 2
#define L_SZ 2048
#define DMODEL 1024
#define DINNER 2048
#define DSTATE 16
#define DTRANK 64
#define M_ROWS (B_SZ * L_SZ)   // 4096

#define CH 32
#define CLEN (L_SZ / CH)
#define CPB 64

#define KSPLIT 8
#define KC (DINNER / KSPLIT)   // 256

typedef short shortx8 __attribute__((ext_vector_type(8)));
typedef float floatx4 __attribute__((ext_vector_type(4)));
typedef float floatx16 __attribute__((ext_vector_type(16)));

__device__ __forceinline__ float softplusf(float x) {
    return fmaxf(x, 0.f) + log1pf(expf(-fabsf(x)));
}
__device__ __forceinline__ float siluf(float x) {
    return x * (1.f / (1.f + expf(-x)));
}

__device__ __forceinline__ void async_ld16(const void* g, void* l) {
    __builtin_amdgcn_global_load_lds(
        (__attribute__((address_space(1))) void*)(unsigned long long)g,
        (__attribute__((address_space(3))) void*)(unsigned int)(unsigned long long)l,
        16, 0, 0);
}

// ---------------------------------------------------------------------------
// R19: dt_proj moved to MFMA. R9's profile exposed dtproj_kernel at ~100us
// (MfmaUtil 0, VALU 28%, HBM 7.5%, 4.85M bank conflicts) -- it was hiding
// just under the top-5 cutoff since R13. dt_proj is matmul-shaped
// (4096x2048x64): now split-bf16 3-term on the R8-verified gemm_bf16_nt
// structure (KP=64 = single staging round, BN=64, 1024 blocks, 3/CU) with
// bias+softplus FUSED in the epilogue (gemm_bf16_sp). Inputs via two tiny
// split2k kernels into the dead-Cp region (consumed before pass3 writes y2).
// Everything else identical to R18 (gemm_8ph R16-exact; xproj BK=64 kept).
// ---------------------------------------------------------------------------

// fp32 [ROWS][KSRC] -> dedup 2-seg ([h|l]) panelized bf16 in LDS-image order.
template <int ROWS, int KSRC>
__global__ __launch_bounds__(256) void split3_kernel(
    const float* __restrict__ src, unsigned short* __restrict__ dst)
{
    constexpr int SEGT = KSRC / 64;
    int i = blockIdx.x * 256 + threadIdx.x;   // ROWS x (KSRC/8) k8-groups
    int row = i & (ROWS - 1);
    int k8s = i / ROWS;
    const float* s = src + (size_t)row * KSRC + k8s * 8;
    float4 v0 = *(const float4*)s;
    float4 v1 = *(const float4*)(s + 4);
    float vs[8] = {v0.x, v0.y, v0.z, v0.w, v1.x, v1.y, v1.z, v1.w};
    unsigned short hsv[8], lsv[8];
#pragma unroll
    for (int j = 0; j < 8; ++j) {
        __hip_bfloat16 h = __float2bfloat16(vs[j]);
        __hip_bfloat16 l = __float2bfloat16(vs[j] - __bfloat162float(h));
        hsv[j] = *(unsigned short*)&h;
        lsv[j] = *(unsigned short*)&l;
    }
    int tloc = k8s >> 3;
    int sh = (k8s >> 2) & 1;
    int k8l = k8s & 3;
    size_t off = ((size_t)(row >> 8) * 4 * SEGT + tloc * 2 + sh) * 8192
               + (size_t)(k8l * 256 + (row & 255)) * 8;
    *(shortx8*)&dst[off] = *(shortx8*)hsv;
    *(shortx8*)&dst[off + (size_t)2 * SEGT * 8192] = *(shortx8*)lsv;
}

// fp32 [rows][LDSRC] (first 64 cols) -> 2-seg bf16 rows [hi 64 | lo 64]
template <int LDSRC>
__global__ __launch_bounds__(256) void split2k_kernel(
    const float* __restrict__ src, unsigned short* __restrict__ dst)
{
    int i = blockIdx.x * 256 + threadIdx.x;   // rows * 64
    int m = i >> 6, k = i & 63;
    float a = src[(size_t)m * LDSRC + k];
    __hip_bfloat16 h = __float2bfloat16(a);
    __hip_bfloat16 l = __float2bfloat16(a - __bfloat162float(h));
    unsigned short* row = dst + (size_t)m * 128;
    row[k] = *(unsigned short*)&h;
    row[64 + k] = *(unsigned short*)&l;
}

// ---------------------------------------------------------------------------
// 8-phase 256x256 pipelined bf16 GEMM over dedup-2-seg panels (R14/R16
// schedule -- verified 92.6-92.8us @ 47% MfmaUtil across 4 rounds/3 boxes).
// ---------------------------------------------------------------------------
template <int KT, int SEGT, int NB, int LDC>
__global__ __launch_bounds__(512, 2) void gemm_8ph(
    const unsigned short* __restrict__ Ap,
    const unsigned short* __restrict__ Bp,
    float* __restrict__ C)
{
    __shared__ unsigned short lds[65536];   // 128KB

    const int tid = threadIdx.x;
    const int lane = tid & 63;
    const int w = tid >> 6;                 // 0..7
    const int wm = w >> 2, wn = w & 3;      // 2 x 4
    const int l15 = lane & 15, l4 = lane >> 4;

    int id = blockIdx.x;
    id = (id & 7) * 32 + (id >> 3);         // bijective XCD swizzle (256 blocks)
    const int bm = id / NB;
    const int bn = id % NB;

    const unsigned short* ga = Ap + (size_t)bm * 4 * SEGT * 8192;
    const unsigned short* gb = Bp + (size_t)bn * 4 * SEGT * 8192;

    const int rA = (l4 * 256 + wm * 128 + l15) * 8;
    const int rB = (l4 * 256 + wn * 64 + l15) * 8;

    floatx4 acc[8][4] = {};
    shortx8 bfr[4];

    auto STAGE = [&](int vt, int ab, int s) {
        int Tv = vt < KT ? vt : KT - 1;    // virtual tiles clamp (counts stay exact)
        int Tm = ab ? (Tv >= SEGT ? Tv - SEGT : Tv)            // B: [h,h,l]
                    : (Tv >= 2 * SEGT ? Tv - 2 * SEGT : Tv);   // A: [h,l,h]
        const unsigned short* src = (ab ? gb : ga) + ((size_t)Tm * 2 + s) * 8192 + tid * 8;
        unsigned short* dst = (unsigned short*)lds + (vt & 1) * 32768 + ab * 16384 + s * 8192 + tid * 8;
        async_ld16(src, dst);
        async_ld16(src + 4096, dst + 4096);
    };

#define MFMA16(MH)                                                                             \
    acc[(MH)*4+0][0] = __builtin_amdgcn_mfma_f32_16x16x32_bf16(af0, bfr[0], acc[(MH)*4+0][0], 0,0,0); \
    acc[(MH)*4+0][1] = __builtin_amdgcn_mfma_f32_16x16x32_bf16(af0, bfr[1], acc[(MH)*4+0][1], 0,0,0); \
    acc[(MH)*4+0][2] = __builtin_amdgcn_mfma_f32_16x16x32_bf16(af0, bfr[2], acc[(MH)*4+0][2], 0,0,0); \
    acc[(MH)*4+0][3] = __builtin_amdgcn_mfma_f32_16x16x32_bf16(af0, bfr[3], acc[(MH)*4+0][3], 0,0,0); \
    acc[(MH)*4+1][0] = __builtin_amdgcn_mfma_f32_16x16x32_bf16(af1, bfr[0], acc[(MH)*4+1][0], 0,0,0); \
    acc[(MH)*4+1][1] = __builtin_amdgcn_mfma_f32_16x16x32_bf16(af1, bfr[1], acc[(MH)*4+1][1], 0,0,0); \
    acc[(MH)*4+1][2] = __builtin_amdgcn_mfma_f32_16x16x32_bf16(af1, bfr[2], acc[(MH)*4+1][2], 0,0,0); \
    acc[(MH)*4+1][3] = __builtin_amdgcn_mfma_f32_16x16x32_bf16(af1, bfr[3], acc[(MH)*4+1][3], 0,0,0); \
    acc[(MH)*4+2][0] = __builtin_amdgcn_mfma_f32_16x16x32_bf16(af2, bfr[0], acc[(MH)*4+2][0], 0,0,0); \
    acc[(MH)*4+2][1] = __builtin_amdgcn_mfma_f32_16x16x32_bf16(af2, bfr[1], acc[(MH)*4+2][1], 0,0,0); \
    acc[(MH)*4+2][2] = __builtin_amdgcn_mfma_f32_16x16x32_bf16(af2, bfr[2], acc[(MH)*4+2][2], 0,0,0); \
    acc[(MH)*4+2][3] = __builtin_amdgcn_mfma_f32_16x16x32_bf16(af2, bfr[3], acc[(MH)*4+2][3], 0,0,0); \
    acc[(MH)*4+3][0] = __builtin_amdgcn_mfma_f32_16x16x32_bf16(af3, bfr[0], acc[(MH)*4+3][0], 0,0,0); \
    acc[(MH)*4+3][1] = __builtin_amdgcn_mfma_f32_16x16x32_bf16(af3, bfr[1], acc[(MH)*4+3][1], 0,0,0); \
    acc[(MH)*4+3][2] = __builtin_amdgcn_mfma_f32_16x16x32_bf16(af3, bfr[2], acc[(MH)*4+3][2], 0,0,0); \
    acc[(MH)*4+3][3] = __builtin_amdgcn_mfma_f32_16x16x32_bf16(af3, bfr[3], acc[(MH)*4+3][3], 0,0,0);

// VM: 1 = counted s_waitcnt vmcnt(4) (phases 4 and 8 only; never 0 mid-loop)
#define PHASE(SLOT, S, MH, SVT, SAB, SS, VM)                                   \
    {                                                                          \
        const unsigned short* Ab = &lds[(SLOT)*32768 + (S)*8192] + rA;         \
        shortx8 af0 = *(const shortx8*)&Ab[((MH)*4 + 0) * 128];                \
        shortx8 af1 = *(const shortx8*)&Ab[((MH)*4 + 1) * 128];                \
        shortx8 af2 = *(const shortx8*)&Ab[((MH)*4 + 2) * 128];                \
        shortx8 af3 = *(const shortx8*)&Ab[((MH)*4 + 3) * 128];                \
        if ((MH) == 0) {                                                       \
            const unsigned short* Bb = &lds[(SLOT)*32768 + 16384 + (S)*8192] + rB; \
            bfr[0] = *(const shortx8*)&Bb[0];                                  \
            bfr[1] = *(const shortx8*)&Bb[128];                                \
            bfr[2] = *(const shortx8*)&Bb[256];                                \
            bfr[3] = *(const shortx8*)&Bb[384];                                \
        }                                                                      \
        STAGE(SVT, SAB, SS);                                                   \
        __builtin_amdgcn_s_barrier();                                          \
        asm volatile("s_waitcnt lgkmcnt(0)" ::: "memory");                     \
        __builtin_amdgcn_s_setprio(1);                                         \
        MFMA16(MH)                                                             \
        __builtin_amdgcn_s_setprio(0);                                         \
        if (VM) { asm volatile("s_waitcnt vmcnt(4)" ::: "memory"); }           \
        __builtin_amdgcn_s_barrier();                                          \
    }

    STAGE(0, 0, 0); STAGE(0, 1, 0); STAGE(0, 0, 1); STAGE(0, 1, 1);
    STAGE(1, 0, 0); STAGE(1, 1, 0);
    asm volatile("s_waitcnt vmcnt(4)" ::: "memory");
    __builtin_amdgcn_s_barrier();

#pragma unroll 1
    for (int i = 0; i < KT / 2; ++i) {
        const int t2 = 2 * i;
        PHASE(0, 0, 0, t2 + 1, 0, 1, 0)
        PHASE(0, 0, 1, t2 + 1, 1, 1, 0)
        PHASE(0, 1, 0, t2 + 2, 0, 0, 0)
        PHASE(0, 1, 1, t2 + 2, 1, 0, 1)   // vmcnt(4): all of t(2i+1) landed
        PHASE(1, 0, 0, t2 + 2, 0, 1, 0)
        PHASE(1, 0, 1, t2 + 2, 1, 1, 0)
        PHASE(1, 1, 0, t2 + 3, 0, 0, 0)
        PHASE(1, 1, 1, t2 + 3, 1, 0, 1)   // vmcnt(4): all of t(2i+2) landed
    }

#undef PHASE
#undef MFMA16

    // epilogue: C/D 16x16: col = lane&15, row = (lane>>4)*4 + reg (m89)
    const int c0 = bn * 256 + wn * 64;
    const int r0 = bm * 256 + wm * 128;
#pragma unroll
    for (int fi = 0; fi < 8; ++fi) {
#pragma unroll
        for (int fj = 0; fj < 4; ++fj) {
            int col = c0 + fj * 16 + l15;
            int rowb = r0 + fi * 16 + l4 * 4;
#pragma unroll
            for (int ri = 0; ri < 4; ++ri)
                C[(size_t)(rowb + ri) * LDC + col] = acc[fi][fj][ri];
        }
    }
}

// ---------------------------------------------------------------------------
// bf16 MFMA GEMM (R8 structure) -- out_proj.
// ---------------------------------------------------------------------------
template <int BN, int KP>
__global__ __launch_bounds__(256) void gemm_bf16_nt(
    const unsigned short* __restrict__ A,
    const unsigned short* __restrict__ Bm,
    float* __restrict__ C, int ldc)
{
    constexpr int TN32 = BN / 64;                 // 32-wide n-tiles per wave
    __shared__ unsigned short As[2 * 8192];       // [seg][t][128 rows][32 k]
    __shared__ unsigned short Bs[2 * BN * 64];    // [seg][t][BN rows][32 k]

    const int tid = threadIdx.x;
    const int w = tid >> 6;
    const int lane = tid & 63;
    const int wm = w >> 1, wn = w & 1;
    const int m0 = blockIdx.y * 128;
    const int n0 = blockIdx.x * BN;

    const int r4 = lane >> 2;
    const int csw = (lane & 3) ^ ((r4 >> 1) & 3);
    const int gk = csw * 8;
    const int l31 = lane & 31;
    const int khalf = lane >> 5;
    const int rsw = (l31 >> 1) & 3;

    floatx16 acc[2][TN32] = {};

    for (int k0 = 0; k0 < KP; k0 += 64) {
#pragma unroll
        for (int seg = 0; seg < 2; ++seg) {
            const unsigned short* Asrc = A + seg * KP;
            const unsigned short* Bsrc = Bm + seg * KP;
#pragma unroll
            for (int t = 0; t < 2; ++t) {
#pragma unroll
                for (int jj = 0; jj < 2; ++jj) {
                    int j = w + jj * 4;
                    async_ld16(Asrc + (size_t)(m0 + j * 16 + r4) * (2 * KP) + k0 + t * 32 + gk,
                               &As[seg * 8192 + t * 4096 + j * 512]);
                }
#pragma unroll
                for (int jj = 0; jj < BN / 64; ++jj) {
                    int j = w + jj * 4;
                    async_ld16(Bsrc + (size_t)(n0 + j * 16 + r4) * (2 * KP) + k0 + t * 32 + gk,
                               &Bs[seg * BN * 64 + t * BN * 32 + j * 512]);
                }
            }
        }
        __syncthreads();

#pragma unroll
        for (int t = 0; t < 2; ++t) {
#pragma unroll
            for (int kk = 0; kk < 2; ++kk) {
                const int pos = ((kk * 2 + khalf) ^ rsw) << 3;
                shortx8 ah[2], al[2], bh[TN32], bl[TN32];
#pragma unroll
                for (int i = 0; i < 2; ++i) {
                    int row = wm * 64 + i * 32 + l31;
                    ah[i] = *(const shortx8*)&As[t * 4096 + row * 32 + pos];
                    al[i] = *(const shortx8*)&As[8192 + t * 4096 + row * 32 + pos];
                }
#pragma unroll
                for (int j = 0; j < TN32; ++j) {
                    int col = wn * (BN / 2) + j * 32 + l31;
                    bh[j] = *(const shortx8*)&Bs[t * BN * 32 + col * 32 + pos];
                    bl[j] = *(const shortx8*)&Bs[BN * 64 + t * BN * 32 + col * 32 + pos];
                }
#pragma unroll
                for (int i = 0; i < 2; ++i)
#pragma unroll
                    for (int j = 0; j < TN32; ++j) {
                        acc[i][j] = __builtin_amdgcn_mfma_f32_32x32x16_bf16(ah[i], bh[j], acc[i][j], 0, 0, 0);
                        acc[i][j] = __builtin_amdgcn_mfma_f32_32x32x16_bf16(ah[i], bl[j], acc[i][j], 0, 0, 0);
                        acc[i][j] = __builtin_amdgcn_mfma_f32_32x32x16_bf16(al[i], bh[j], acc[i][j], 0, 0, 0);
                    }
            }
        }
        __syncthreads();
    }

#pragma unroll
    for (int i = 0; i < 2; ++i) {
#pragma unroll
        for (int j = 0; j < TN32; ++j) {
            int col = n0 + wn * (BN / 2) + j * 32 + l31;
#pragma unroll
            for (int r = 0; r < 16; ++r) {
                int row = m0 + wm * 64 + i * 32 + (r & 3) + 8 * (r >> 2) + 4 * khalf;
                C[(size_t)row * ldc + col] = acc[i][j][r];
            }
        }
    }
}

// ---------------------------------------------------------------------------
// dt_proj GEMM: same structure as gemm_bf16_nt (BN=64, KP=64 -> single
// staging round), epilogue fuses bias + softplus. A=[4096][128] 2-seg,
// B=[2048][128] 2-seg, C=dbuf [4096][2048] fp32.
// ---------------------------------------------------------------------------
template <int BN, int KP>
__global__ __launch_bounds__(256) void gemm_bf16_sp(
    const unsigned short* __restrict__ A,
    const unsigned short* __restrict__ Bm,
    float* __restrict__ C, int ldc, const float* __restrict__ bias)
{
    constexpr int TN32 = BN / 64;
    __shared__ unsigned short As[2 * 8192];
    __shared__ unsigned short Bs[2 * BN * 64];

    const int tid = threadIdx.x;
    const int w = tid >> 6;
    const int lane = tid & 63;
    const int wm = w >> 1, wn = w & 1;
    const int m0 = blockIdx.y * 128;
    const int n0 = blockIdx.x * BN;

    const int r4 = lane >> 2;
    const int csw = (lane & 3) ^ ((r4 >> 1) & 3);
    const int gk = csw * 8;
    const int l31 = lane & 31;
    const int khalf = lane >> 5;
    const int rsw = (l31 >> 1) & 3;

    floatx16 acc[2][TN32] = {};

    for (int k0 = 0; k0 < KP; k0 += 64) {
#pragma unroll
        for (int seg = 0; seg < 2; ++seg) {
            const unsigned short* Asrc = A + seg * KP;
            const unsigned short* Bsrc = Bm + seg * KP;
#pragma unroll
            for (int t = 0; t < 2; ++t) {
#pragma unroll
                for (int jj = 0; jj < 2; ++jj) {
                    int j = w + jj * 4;
                    async_ld16(Asrc + (size_t)(m0 + j * 16 + r4) * (2 * KP) + k0 + t * 32 + gk,
                               &As[seg * 8192 + t * 4096 + j * 512]);
                }
#pragma unroll
                for (int jj = 0; jj < BN / 64; ++jj) {
                    int j = w + jj * 4;
                    async_ld16(Bsrc + (size_t)(n0 + j * 16 + r4) * (2 * KP) + k0 + t * 32 + gk,
                               &Bs[seg * BN * 64 + t * BN * 32 + j * 512]);
                }
            }
        }
        __syncthreads();

#pragma unroll
        for (int t = 0; t < 2; ++t) {
#pragma unroll
            for (int kk = 0; kk < 2; ++kk) {
                const int pos = ((kk * 2 + khalf) ^ rsw) << 3;
                shortx8 ah[2], al[2], bh[TN32], bl[TN32];
#pragma unroll
                for (int i = 0; i < 2; ++i) {
                    int row = wm * 64 + i * 32 + l31;
                    ah[i] = *(const shortx8*)&As[t * 4096 + row * 32 + pos];
                    al[i] = *(const shortx8*)&As[8192 + t * 4096 + row * 32 + pos];
                }
#pragma unroll
                for (int j = 0; j < TN32; ++j) {
                    int col = wn * (BN / 2) + j * 32 + l31;
                    bh[j] = *(const shortx8*)&Bs[t * BN * 32 + col * 32 + pos];
                    bl[j] = *(const shortx8*)&Bs[BN * 64 + t * BN * 32 + col * 32 + pos];
                }
#pragma unroll
                for (int i = 0; i < 2; ++i)
#pragma unroll
                    for (int j = 0; j < TN32; ++j) {
                        acc[i][j] = __builtin_amdgcn_mfma_f32_32x32x16_bf16(ah[i], bh[j], acc[i][j], 0, 0, 0);
                        acc[i][j] = __builtin_amdgcn_mfma_f32_32x32x16_bf16(ah[i], bl[j], acc[i][j], 0, 0, 0);
                        acc[i][j] = __builtin_amdgcn_mfma_f32_32x32x16_bf16(al[i], bh[j], acc[i][j], 0, 0, 0);
                    }
            }
        }
        __syncthreads();
    }

#pragma unroll
    for (int i = 0; i < 2; ++i) {
#pragma unroll
        for (int j = 0; j < TN32; ++j) {
            int col = n0 + wn * (BN / 2) + j * 32 + l31;
            float bz = bias[col];
#pragma unroll
            for (int r = 0; r < 16; ++r) {
                int row = m0 + wm * 64 + i * 32 + (r & 3) + 8 * (r >> 2) + 4 * khalf;
                C[(size_t)row * ldc + col] = softplusf(acc[i][j][r] + bz);
            }
        }
    }
}

// ---------------------------------------------------------------------------
// fp32 -> 2-segment split-bf16: row = [hi (K) | lo (K)], stride 2K (out_proj)
// ---------------------------------------------------------------------------
__global__ __launch_bounds__(256) void split2_kernel(
    const float* __restrict__ src, unsigned short* __restrict__ dst, int K)
{
    int i = blockIdx.x * 256 + threadIdx.x;
    int m = i / K;
    int k = i - m * K;
    float a = src[i];
    __hip_bfloat16 h = __float2bfloat16(a);
    __hip_bfloat16 l = __float2bfloat16(a - __bfloat162float(h));
    unsigned short* row = dst + (size_t)m * 2 * K;
    row[k] = *(unsigned short*)&h;
    row[K + k] = *(unsigned short*)&l;
}

// ---------------------------------------------------------------------------
// x_proj split-K partial GEMM + reduce (BK=64, R18)
// ---------------------------------------------------------------------------
__global__ __launch_bounds__(256) void xproj_splitk(
    const float* __restrict__ u, const float* __restrict__ Wx,
    float* __restrict__ Cp)
{
    __shared__ float As[64][68];     // [k][row]
    __shared__ float Bs[64][100];    // [k][row]

    const int tid = threadIdx.x;
    const int ks = blockIdx.x;
    const int m0 = blockIdx.y * 64;
    const int tx = tid & 15;
    const int ty = tid >> 4;

    float acc[4][6] = {};

    for (int k0 = ks * KC; k0 < (ks + 1) * KC; k0 += 64) {
        for (int idx = tid * 4; idx < 64 * 64; idx += 1024) {
            int row = idx >> 6, kk = idx & 63;
            float4 v = *(const float4*)&u[(size_t)(m0 + row) * DINNER + k0 + kk];
            As[kk + 0][row] = v.x;
            As[kk + 1][row] = v.y;
            As[kk + 2][row] = v.z;
            As[kk + 3][row] = v.w;
        }
        for (int idx = tid * 4; idx < 96 * 64; idx += 1024) {
            int row = idx >> 6, kk = idx & 63;
            float4 v = *(const float4*)&Wx[(size_t)row * DINNER + k0 + kk];
            Bs[kk + 0][row] = v.x;
            Bs[kk + 1][row] = v.y;
            Bs[kk + 2][row] = v.z;
            Bs[kk + 3][row] = v.w;
        }
        __syncthreads();

#pragma unroll 8
        for (int k = 0; k < 64; ++k) {
            float a[4], b[6];
#pragma unroll
            for (int i = 0; i < 4; ++i) a[i] = As[k][ty * 4 + i];
#pragma unroll
            for (int j = 0; j < 6; ++j) b[j] = Bs[k][tx * 6 + j];
#pragma unroll
            for (int i = 0; i < 4; ++i)
#pragma unroll
                for (int j = 0; j < 6; ++j) acc[i][j] = fmaf(a[i], b[j], acc[i][j]);
        }
        __syncthreads();
    }

    float* outp = Cp + ((size_t)ks * M_ROWS + m0) * 96;
#pragma unroll
    for (int i = 0; i < 4; ++i)
#pragma unroll
        for (int j = 0; j < 6; ++j)
            outp[(ty * 4 + i) * 96 + tx * 6 + j] = acc[i][j];
}

__global__ __launch_bounds__(256) void xproj_reduce(
    const float* __restrict__ Cp, float* __restrict__ xdbl)
{
    int i = blockIdx.x * 256 + threadIdx.x;
    float s = 0.f;
#pragma unroll
    for (int c = 0; c < KSPLIT; ++c)
        s += Cp[(size_t)c * M_ROWS * 96 + i];
    xdbl[i] = s;
}

// ---------------------------------------------------------------------------
// conv + silu, float4 over channels
// ---------------------------------------------------------------------------
__global__ __launch_bounds__(256) void conv_silu_v4(
    const float* __restrict__ xz, const float* __restrict__ cw,
    const float* __restrict__ cb, float* __restrict__ u)
{
    int i = blockIdx.x * 256 + threadIdx.x;      // over M_ROWS * 512
    int dq = (i & 511) << 2;
    int bl = i >> 9;
    int b = bl >> 11;
    int l = bl & 2047;

    float4 W0 = *(const float4*)&cw[(dq + 0) * 4];
    float4 W1 = *(const float4*)&cw[(dq + 1) * 4];
    float4 W2 = *(const float4*)&cw[(dq + 2) * 4];
    float4 W3 = *(const float4*)&cw[(dq + 3) * 4];
    float4 acc = *(const float4*)&cb[dq];

#pragma unroll
    for (int k = 0; k < 4; ++k) {
        int ls = l + k - 3;
        if (ls >= 0) {
            float4 v = *(const float4*)&xz[((size_t)(b << 11) + ls) * 4096 + dq];
            acc.x = fmaf(v.x, ((const float*)&W0)[k], acc.x);
            acc.y = fmaf(v.y, ((const float*)&W1)[k], acc.y);
            acc.z = fmaf(v.z, ((const float*)&W2)[k], acc.z);
            acc.w = fmaf(v.w, ((const float*)&W3)[k], acc.w);
        }
    }
    float4 r = make_float4(siluf(acc.x), siluf(acc.y), siluf(acc.z), siluf(acc.w));
    *(float4*)&u[(size_t)bl * DINNER + dq] = r;
}

// ---------------------------------------------------------------------------
// Chunked selective scan (3 passes). PASS3 fuses gate + split-bf16 y2
// (linear 2-seg layout [4096][hi 2048 | lo 2048]).
// ---------------------------------------------------------------------------
template <bool PASS3>
__global__ __launch_bounds__(256) void scan_chunk(
    const float* __restrict__ dbuf, const float* __restrict__ ubuf,
    const float* __restrict__ xdbl, const float* __restrict__ A_log,
    const float* __restrict__ Dv,
    float* __restrict__ Pbuf, float* __restrict__ Sbuf,
    const float* __restrict__ xz, unsigned short* __restrict__ y2)
{
    __shared__ float sd[16][CPB];
    __shared__ float su[16][CPB];
    __shared__ float sB[16][DSTATE];
    __shared__ float sC[16][DSTATE];

    const int tid = threadIdx.x;
    const int c    = blockIdx.x % CH;
    const int dblk = (blockIdx.x / CH) % (DINNER / CPB);
    const int b    = blockIdx.x / (CH * (DINNER / CPB));
    const int d0 = dblk * CPB;
    const int dg = tid >> 2;
    const int q  = tid & 3;
    const int d  = d0 + dg;
    const size_t base_bl = (size_t)b * L_SZ + (size_t)c * CLEN;

    float Ac[4], h[4];
    float sdl = 0.f;
#pragma unroll
    for (int j = 0; j < 4; ++j)
        Ac[j] = -expf(A_log[d * DSTATE + 4 * q + j]);
    const size_t psoff = (((size_t)b * CH + c) * DINNER + d0) * DSTATE + (size_t)tid * 4;
    if (PASS3) {
        float4 h0 = *(const float4*)&Sbuf[psoff];
        h[0] = h0.x; h[1] = h0.y; h[2] = h0.z; h[3] = h0.w;
    } else {
        h[0] = h[1] = h[2] = h[3] = 0.f;
    }
    const float Dd = PASS3 ? Dv[d] : 0.f;

    const int ls = tid >> 4;
    const int g4 = (tid & 15) * 4;
    const int ln = tid & 15;

    float4 r_d = *(const float4*)&dbuf[(base_bl + ls) * DINNER + d0 + g4];
    float4 r_u = *(const float4*)&ubuf[(base_bl + ls) * DINNER + d0 + g4];
    float r_B = xdbl[(base_bl + ls) * 96 + 64 + ln];
    float r_C = xdbl[(base_bl + ls) * 96 + 80 + ln];

    for (int l0 = 0; l0 < CLEN; l0 += 16) {
        __syncthreads();
        *(float4*)&sd[ls][g4] = r_d;
        *(float4*)&su[ls][g4] = r_u;
        sB[ls][ln] = r_B;
        sC[ls][ln] = r_C;
        __syncthreads();

        if (l0 + 16 < CLEN) {
            r_d = *(const float4*)&dbuf[(base_bl + l0 + 16 + ls) * DINNER + d0 + g4];
            r_u = *(const float4*)&ubuf[(base_bl + l0 + 16 + ls) * DINNER + d0 + g4];
            r_B = xdbl[(base_bl + l0 + 16 + ls) * 96 + 64 + ln];
            r_C = xdbl[(base_bl + l0 + 16 + ls) * 96 + 80 + ln];
        }

#pragma unroll
        for (int s = 0; s < 16; ++s) {
            float dl = sd[s][dg];
            float ul = su[s][dg];
            float4 Bv = *(float4*)&sB[s][4 * q];
            float dbu = dl * ul;
            float dA0 = expf(dl * Ac[0]);
            float dA1 = expf(dl * Ac[1]);
            float dA2 = expf(dl * Ac[2]);
            float dA3 = expf(dl * Ac[3]);
            h[0] = fmaf(dA0, h[0], dbu * Bv.x);
            h[1] = fmaf(dA1, h[1], dbu * Bv.y);
            h[2] = fmaf(dA2, h[2], dbu * Bv.z);
            h[3] = fmaf(dA3, h[3], dbu * Bv.w);
            if (!PASS3) {
                sdl += dl;
            } else {
                float4 Cv = *(float4*)&sC[s][4 * q];
                float y = h[0] * Cv.x + h[1] * Cv.y + h[2] * Cv.z + h[3] * Cv.w;
                y += __shfl_xor(y, 1);
                y += __shfl_xor(y, 2);
                if (q == 0) su[s][dg] = fmaf(ul, Dd, y);
            }
        }

        if (PASS3) {
            __syncthreads();
            size_t row = base_bl + l0 + ls;
            float4 yv = *(float4*)&su[ls][g4];
            float4 rv = *(const float4*)&xz[row * 4096 + 2048 + d0 + g4];
            float a0 = yv.x * siluf(rv.x);
            float a1 = yv.y * siluf(rv.y);
            float a2 = yv.z * siluf(rv.z);
            float a3 = yv.w * siluf(rv.w);
            __hip_bfloat16 h0 = __float2bfloat16(a0), h1 = __float2bfloat16(a1);
            __hip_bfloat16 h2 = __float2bfloat16(a2), h3 = __float2bfloat16(a3);
            __hip_bfloat16 l0b = __float2bfloat16(a0 - __bfloat162float(h0));
            __hip_bfloat16 l1b = __float2bfloat16(a1 - __bfloat162float(h1));
            __hip_bfloat16 l2b = __float2bfloat16(a2 - __bfloat162float(h2));
            __hip_bfloat16 l3b = __float2bfloat16(a3 - __bfloat162float(h3));
            ushort4 hv = make_ushort4(*(unsigned short*)&h0, *(unsigned short*)&h1,
                                      *(unsigned short*)&h2, *(unsigned short*)&h3);
            ushort4 lv = make_ushort4(*(unsigned short*)&l0b, *(unsigned short*)&l1b,
                                      *(unsigned short*)&l2b, *(unsigned short*)&l3b);
            unsigned short* yrow = y2 + row * 2 * DINNER + d0 + g4;
            *(ushort4*)&yrow[0] = hv;
            *(ushort4*)&yrow[DINNER] = lv;
        }
    }

    if (!PASS3) {
        *(float4*)&Pbuf[psoff] = make_float4(expf(Ac[0] * sdl), expf(Ac[1] * sdl),
                                             expf(Ac[2] * sdl), expf(Ac[3] * sdl));
        *(float4*)&Sbuf[psoff] = make_float4(h[0], h[1], h[2], h[3]);
    }
}

__global__ __launch_bounds__(256) void scan_combine(
    const float* __restrict__ Pbuf, float* __restrict__ Sbuf)
{
    int t = blockIdx.x * 256 + threadIdx.x;
    int b = t >> 15;
    int rem = t & 32767;
    size_t base = (size_t)b * CH * DINNER * DSTATE + rem;
    float H = 0.f;
#pragma unroll 4
    for (int c = 0; c < CH; ++c) {
        size_t off = base + (size_t)c * DINNER * DSTATE;
        float S = Sbuf[off];
        float P = Pbuf[off];
        Sbuf[off] = H;
        H = fmaf(P, H, S);
    }
}

// ---------------------------------------------------------------------------
extern "C" void kernel_launch(void* const* d_in, const int* in_sizes, int n_in,
                              void* d_out, int out_size, void* d_ws, size_t ws_size,
                              hipStream_t stream)
{
    const float* x          = (const float*)d_in[0];
    const float* in_proj_w  = (const float*)d_in[1];
    const float* conv_w     = (const float*)d_in[2];
    const float* conv_b     = (const float*)d_in[3];
    const float* x_proj_w   = (const float*)d_in[4];
    const float* dt_proj_w  = (const float*)d_in[5];
    const float* dt_proj_b  = (const float*)d_in[6];
    const float* A_log      = (const float*)d_in[7];
    const float* Dv         = (const float*)d_in[8];
    const float* out_proj_w = (const float*)d_in[9];
    float* out = (float*)d_out;

    // workspace layout (bytes):
    char* w = (char*)d_ws;
    float* xz   = (float*)(w);                       // 64 MB
    float* u    = (float*)(w + 67108864);            // 32 MB (written step 3)
    float* dbuf = (float*)(w + 100663296);           // 32 MB (written step 5)
    float* xdbl = (float*)(w + 134217728);           // 1.5 MB
    float* Pbuf = (float*)(w + 135790592);           // 8 MB (dead after combine)
    float* Sbuf = (float*)(w + 144179200);           // 8 MB (ends 152567808)
    unsigned short* y2  = (unsigned short*)(w + 152567808);   // 32 MB [4096][4096] 2-seg
    unsigned short* w2b = (unsigned short*)(w + 135790592);   // 8 MB over Pbuf (dead at 7)
    float* Cp = (float*)(w + 152567808);             // xproj partials (dead at 4, pre-y2)
    // dt_proj 2-seg inputs; over dead Cp region, consumed before pass3 writes y2
    unsigned short* dt2  = (unsigned short*)(w + 152567808);            // 1 MB
    unsigned short* wdt2 = (unsigned short*)(w + 152567808 + 1048576);  // 0.5 MB
    // dedup 2-seg panels for in_proj; ALIAS u / dbuf (dead after step 2)
    unsigned short* x2p  = (unsigned short*)(w + 67108864);   // 16 MB over u
    unsigned short* w2ap = (unsigned short*)(w + 100663296);  // 16 MB over dbuf

    // 1) split x / in_proj_w -> dedup 2-seg panels (K'=3072 traversal)
    split3_kernel<4096, 1024><<<2048, 256, 0, stream>>>(x, x2p);
    split3_kernel<4096, 1024><<<2048, 256, 0, stream>>>(in_proj_w, w2ap);
    // 2) in_proj: 8-phase GEMM, KT=48, SEGT=16, NB=16 (R16-exact, ~93us)
    gemm_8ph<48, 16, 16, 4096><<<256, 512, 0, stream>>>(x2p, w2ap, xz);
    // 3) conv + silu -> u (overwrites x2p, dead)
    conv_silu_v4<<<(M_ROWS * 512) / 256, 256, 0, stream>>>(xz, conv_w, conv_b, u);
    // 4) x_proj via split-K (BK=64); Cp dead after reduce
    {
        dim3 g(KSPLIT, M_ROWS / 64);
        xproj_splitk<<<g, 256, 0, stream>>>(u, x_proj_w, Cp);
        xproj_reduce<<<(M_ROWS * 96) / 256, 256, 0, stream>>>(Cp, xdbl);
    }
    // 5) dt_proj on MFMA: split dt inputs to 2-seg bf16, GEMM + fused
    //    bias/softplus -> dbuf (overwrites w2ap, dead)
    {
        split2k_kernel<96><<<1024, 256, 0, stream>>>(xdbl, dt2);
        split2k_kernel<64><<<512, 256, 0, stream>>>(dt_proj_w, wdt2);
        dim3 g(DINNER / 64, M_ROWS / 128);
        gemm_bf16_sp<64, 64><<<g, 256, 0, stream>>>(dt2, wdt2, dbuf, DINNER, dt_proj_b);
    }
    // 6) chunked selective scan; pass3 fuses gate + linear 2-seg split into y2
    {
        const int nblk = B_SZ * (DINNER / CPB) * CH;
        scan_chunk<false><<<nblk, 256, 0, stream>>>(dbuf, u, xdbl, A_log, Dv, Pbuf, Sbuf, nullptr, nullptr);
        scan_combine<<<B_SZ * DINNER * DSTATE / 256, 256, 0, stream>>>(Pbuf, Sbuf);
        scan_chunk<true><<<nblk, 256, 0, stream>>>(dbuf, u, xdbl, A_log, Dv, nullptr, Sbuf, xz, y2);
    }
    // 7) split out_proj_w (2-seg linear; Pbuf dead after combine)
    split2_kernel<<<(DMODEL * DINNER) / 256, 256, 0, stream>>>(out_proj_w, w2b, DINNER);
    // 8) out_proj via 32x32x16 MFMA (R8 structure)
    {
        dim3 g(1024 / 64, M_ROWS / 128);
        gemm_bf16_nt<64, 2048><<<g, 256, 0, stream>>>(y2, w2b, out, 1024);
    }
}

// Round 11
// 500.421 us; speedup vs baseline: 1.0194x; 1.0192x over previous
//
#include <hip/hip_runtime.h>
#include <hip/hip_bf16.h>
#include <math.h>

#define B_SZ 2
#define L_SZ 2048
#define DMODEL 1024
#define DINNER 2048
#define DSTATE 16
#define DTRANK 64
#define M_ROWS (B_SZ * L_SZ)   // 4096

#define CH 32
#define CLEN (L_SZ / CH)
#define CPB 64

#define KSPLIT 8
#define KC (DINNER / KSPLIT)   // 256

typedef short shortx8 __attribute__((ext_vector_type(8)));
typedef float floatx4 __attribute__((ext_vector_type(4)));
typedef float floatx16 __attribute__((ext_vector_type(16)));

__device__ __forceinline__ float softplusf(float x) {
    return fmaxf(x, 0.f) + log1pf(expf(-fabsf(x)));
}
__device__ __forceinline__ float siluf(float x) {
    return x * (1.f / (1.f + expf(-x)));
}

__device__ __forceinline__ void async_ld16(const void* g, void* l) {
    __builtin_amdgcn_global_load_lds(
        (__attribute__((address_space(1))) void*)(unsigned long long)g,
        (__attribute__((address_space(3))) void*)(unsigned int)(unsigned long long)l,
        16, 0, 0);
}

// ---------------------------------------------------------------------------
// R20: (a) out_proj rebuilt as 128x128-tile, 512-thread (8-wave) variant of
// the R8-verified 2-barrier GEMM. BN=64 ran 472 TF (R0: 109us); the BN=128
// geometry ran 941 TF (R0 in_proj) but at 256 threads would give 1 wave/SIMD
// at grid=256 (R1 catastrophe). 512 thr -> 2 waves/SIMD at 1 block/CU (same
// occupancy class as gemm_8ph @47%). acc = 2x floatx16 = 32 VGPR. Direct C
// write (no R15 partial-traffic trap). Tripwire: if gemm_bf16_128x128 shows
// up in top-5 (>~95us), 1-block/CU penalty won -> revert.
// (b) split3 line-read remap: old mapping read 32B per lane at 4KB stride
// (25% line use, ~x4 fetch on 32MB); new mapping reads one FULL 128B line
// per lane (4 k8-groups/thread), writes stay 1KB-coalesced per (seg,k8l).
// Everything else byte-identical to R19/R10.
// ---------------------------------------------------------------------------

// fp32 [ROWS][KSRC] -> dedup 2-seg ([h|l]) panelized bf16 in LDS-image order.
// Each thread: one 128B line (32 floats = 4 k8-groups) of one row.
template <int ROWS, int KSRC>
__global__ __launch_bounds__(256) void split3_kernel(
    const float* __restrict__ src, unsigned short* __restrict__ dst)
{
    constexpr int SEGT = KSRC / 64;
    int i = blockIdx.x * 256 + threadIdx.x;   // ROWS x (KSRC/32) line-groups
    int row = i & (ROWS - 1);
    int g = i / ROWS;                         // 0..KSRC/32-1
    const float* s = src + (size_t)row * KSRC + g * 32;
    // k8s = 4g+q: tloc = g>>1, sh = g&1, k8l = q  (q < 4)
    int tloc = g >> 1;
    int sh = g & 1;
    size_t base = ((size_t)(row >> 8) * 4 * SEGT + tloc * 2 + sh) * 8192
                + (size_t)(row & 255) * 8;
#pragma unroll
    for (int q = 0; q < 4; ++q) {
        float4 v0 = *(const float4*)(s + q * 8);
        float4 v1 = *(const float4*)(s + q * 8 + 4);
        float fs[8] = {v0.x, v0.y, v0.z, v0.w, v1.x, v1.y, v1.z, v1.w};
        shortx8 hv, lv;
#pragma unroll
        for (int j = 0; j < 8; ++j) {
            __hip_bfloat16 h = __float2bfloat16(fs[j]);
            __hip_bfloat16 l = __float2bfloat16(fs[j] - __bfloat162float(h));
            hv[j] = *(unsigned short*)&h;
            lv[j] = *(unsigned short*)&l;
        }
        size_t off = base + (size_t)q * 2048;
        *(shortx8*)&dst[off] = hv;
        *(shortx8*)&dst[off + (size_t)2 * SEGT * 8192] = lv;
    }
}

// fp32 [rows][LDSRC] (first 64 cols) -> 2-seg bf16 rows [hi 64 | lo 64]
template <int LDSRC>
__global__ __launch_bounds__(256) void split2k_kernel(
    const float* __restrict__ src, unsigned short* __restrict__ dst)
{
    int i = blockIdx.x * 256 + threadIdx.x;   // rows * 64
    int m = i >> 6, k = i & 63;
    float a = src[(size_t)m * LDSRC + k];
    __hip_bfloat16 h = __float2bfloat16(a);
    __hip_bfloat16 l = __float2bfloat16(a - __bfloat162float(h));
    unsigned short* row = dst + (size_t)m * 128;
    row[k] = *(unsigned short*)&h;
    row[64 + k] = *(unsigned short*)&l;
}

// ---------------------------------------------------------------------------
// 8-phase 256x256 pipelined bf16 GEMM over dedup-2-seg panels (R14/R16
// schedule -- verified 92.6-96us @ 46-47% MfmaUtil across 5 rounds/4 boxes).
// ---------------------------------------------------------------------------
template <int KT, int SEGT, int NB, int LDC>
__global__ __launch_bounds__(512, 2) void gemm_8ph(
    const unsigned short* __restrict__ Ap,
    const unsigned short* __restrict__ Bp,
    float* __restrict__ C)
{
    __shared__ unsigned short lds[65536];   // 128KB

    const int tid = threadIdx.x;
    const int lane = tid & 63;
    const int w = tid >> 6;                 // 0..7
    const int wm = w >> 2, wn = w & 3;      // 2 x 4
    const int l15 = lane & 15, l4 = lane >> 4;

    int id = blockIdx.x;
    id = (id & 7) * 32 + (id >> 3);         // bijective XCD swizzle (256 blocks)
    const int bm = id / NB;
    const int bn = id % NB;

    const unsigned short* ga = Ap + (size_t)bm * 4 * SEGT * 8192;
    const unsigned short* gb = Bp + (size_t)bn * 4 * SEGT * 8192;

    const int rA = (l4 * 256 + wm * 128 + l15) * 8;
    const int rB = (l4 * 256 + wn * 64 + l15) * 8;

    floatx4 acc[8][4] = {};
    shortx8 bfr[4];

    auto STAGE = [&](int vt, int ab, int s) {
        int Tv = vt < KT ? vt : KT - 1;    // virtual tiles clamp (counts stay exact)
        int Tm = ab ? (Tv >= SEGT ? Tv - SEGT : Tv)            // B: [h,h,l]
                    : (Tv >= 2 * SEGT ? Tv - 2 * SEGT : Tv);   // A: [h,l,h]
        const unsigned short* src = (ab ? gb : ga) + ((size_t)Tm * 2 + s) * 8192 + tid * 8;
        unsigned short* dst = (unsigned short*)lds + (vt & 1) * 32768 + ab * 16384 + s * 8192 + tid * 8;
        async_ld16(src, dst);
        async_ld16(src + 4096, dst + 4096);
    };

#define MFMA16(MH)                                                                             \
    acc[(MH)*4+0][0] = __builtin_amdgcn_mfma_f32_16x16x32_bf16(af0, bfr[0], acc[(MH)*4+0][0], 0,0,0); \
    acc[(MH)*4+0][1] = __builtin_amdgcn_mfma_f32_16x16x32_bf16(af0, bfr[1], acc[(MH)*4+0][1], 0,0,0); \
    acc[(MH)*4+0][2] = __builtin_amdgcn_mfma_f32_16x16x32_bf16(af0, bfr[2], acc[(MH)*4+0][2], 0,0,0); \
    acc[(MH)*4+0][3] = __builtin_amdgcn_mfma_f32_16x16x32_bf16(af0, bfr[3], acc[(MH)*4+0][3], 0,0,0); \
    acc[(MH)*4+1][0] = __builtin_amdgcn_mfma_f32_16x16x32_bf16(af1, bfr[0], acc[(MH)*4+1][0], 0,0,0); \
    acc[(MH)*4+1][1] = __builtin_amdgcn_mfma_f32_16x16x32_bf16(af1, bfr[1], acc[(MH)*4+1][1], 0,0,0); \
    acc[(MH)*4+1][2] = __builtin_amdgcn_mfma_f32_16x16x32_bf16(af1, bfr[2], acc[(MH)*4+1][2], 0,0,0); \
    acc[(MH)*4+1][3] = __builtin_amdgcn_mfma_f32_16x16x32_bf16(af1, bfr[3], acc[(MH)*4+1][3], 0,0,0); \
    acc[(MH)*4+2][0] = __builtin_amdgcn_mfma_f32_16x16x32_bf16(af2, bfr[0], acc[(MH)*4+2][0], 0,0,0); \
    acc[(MH)*4+2][1] = __builtin_amdgcn_mfma_f32_16x16x32_bf16(af2, bfr[1], acc[(MH)*4+2][1], 0,0,0); \
    acc[(MH)*4+2][2] = __builtin_amdgcn_mfma_f32_16x16x32_bf16(af2, bfr[2], acc[(MH)*4+2][2], 0,0,0); \
    acc[(MH)*4+2][3] = __builtin_amdgcn_mfma_f32_16x16x32_bf16(af2, bfr[3], acc[(MH)*4+2][3], 0,0,0); \
    acc[(MH)*4+3][0] = __builtin_amdgcn_mfma_f32_16x16x32_bf16(af3, bfr[0], acc[(MH)*4+3][0], 0,0,0); \
    acc[(MH)*4+3][1] = __builtin_amdgcn_mfma_f32_16x16x32_bf16(af3, bfr[1], acc[(MH)*4+3][1], 0,0,0); \
    acc[(MH)*4+3][2] = __builtin_amdgcn_mfma_f32_16x16x32_bf16(af3, bfr[2], acc[(MH)*4+3][2], 0,0,0); \
    acc[(MH)*4+3][3] = __builtin_amdgcn_mfma_f32_16x16x32_bf16(af3, bfr[3], acc[(MH)*4+3][3], 0,0,0);

// VM: 1 = counted s_waitcnt vmcnt(4) (phases 4 and 8 only; never 0 mid-loop)
#define PHASE(SLOT, S, MH, SVT, SAB, SS, VM)                                   \
    {                                                                          \
        const unsigned short* Ab = &lds[(SLOT)*32768 + (S)*8192] + rA;         \
        shortx8 af0 = *(const shortx8*)&Ab[((MH)*4 + 0) * 128];                \
        shortx8 af1 = *(const shortx8*)&Ab[((MH)*4 + 1) * 128];                \
        shortx8 af2 = *(const shortx8*)&Ab[((MH)*4 + 2) * 128];                \
        shortx8 af3 = *(const shortx8*)&Ab[((MH)*4 + 3) * 128];                \
        if ((MH) == 0) {                                                       \
            const unsigned short* Bb = &lds[(SLOT)*32768 + 16384 + (S)*8192] + rB; \
            bfr[0] = *(const shortx8*)&Bb[0];                                  \
            bfr[1] = *(const shortx8*)&Bb[128];                                \
            bfr[2] = *(const shortx8*)&Bb[256];                                \
            bfr[3] = *(const shortx8*)&Bb[384];                                \
        }                                                                      \
        STAGE(SVT, SAB, SS);                                                   \
        __builtin_amdgcn_s_barrier();                                          \
        asm volatile("s_waitcnt lgkmcnt(0)" ::: "memory");                     \
        __builtin_amdgcn_s_setprio(1);                                         \
        MFMA16(MH)                                                             \
        __builtin_amdgcn_s_setprio(0);                                         \
        if (VM) { asm volatile("s_waitcnt vmcnt(4)" ::: "memory"); }           \
        __builtin_amdgcn_s_barrier();                                          \
    }

    STAGE(0, 0, 0); STAGE(0, 1, 0); STAGE(0, 0, 1); STAGE(0, 1, 1);
    STAGE(1, 0, 0); STAGE(1, 1, 0);
    asm volatile("s_waitcnt vmcnt(4)" ::: "memory");
    __builtin_amdgcn_s_barrier();

#pragma unroll 1
    for (int i = 0; i < KT / 2; ++i) {
        const int t2 = 2 * i;
        PHASE(0, 0, 0, t2 + 1, 0, 1, 0)
        PHASE(0, 0, 1, t2 + 1, 1, 1, 0)
        PHASE(0, 1, 0, t2 + 2, 0, 0, 0)
        PHASE(0, 1, 1, t2 + 2, 1, 0, 1)   // vmcnt(4): all of t(2i+1) landed
        PHASE(1, 0, 0, t2 + 2, 0, 1, 0)
        PHASE(1, 0, 1, t2 + 2, 1, 1, 0)
        PHASE(1, 1, 0, t2 + 3, 0, 0, 0)
        PHASE(1, 1, 1, t2 + 3, 1, 0, 1)   // vmcnt(4): all of t(2i+2) landed
    }

#undef PHASE
#undef MFMA16

    // epilogue: C/D 16x16: col = lane&15, row = (lane>>4)*4 + reg (m89)
    const int c0 = bn * 256 + wn * 64;
    const int r0 = bm * 256 + wm * 128;
#pragma unroll
    for (int fi = 0; fi < 8; ++fi) {
#pragma unroll
        for (int fj = 0; fj < 4; ++fj) {
            int col = c0 + fj * 16 + l15;
            int rowb = r0 + fi * 16 + l4 * 4;
#pragma unroll
            for (int ri = 0; ri < 4; ++ri)
                C[(size_t)(rowb + ri) * LDC + col] = acc[fi][fj][ri];
        }
    }
}

// ---------------------------------------------------------------------------
// out_proj: 128x128-tile, 512-thread (8-wave) bf16 GEMM, R8 sync structure.
// Waves: wm = w>>2 (row half), wn = w&3 (col quarter); per wave 64x32 out.
// Staging: per (seg,t) each wave stages A j-group w and B j-group w
// (identical lane->row/chunk XOR-swizzle mapping as gemm_bf16_nt).
// Grid (N/128, M/128) = (8, 32) = 256 blocks, 1/CU, 2 waves/SIMD.
// ---------------------------------------------------------------------------
template <int KP>
__global__ __launch_bounds__(512) void gemm_bf16_128x128(
    const unsigned short* __restrict__ A,
    const unsigned short* __restrict__ Bm,
    float* __restrict__ C, int ldc)
{
    __shared__ unsigned short As[2 * 8192];    // [seg][t][8 j][512]
    __shared__ unsigned short Bs[2 * 8192];

    const int tid = threadIdx.x;
    const int w = tid >> 6;          // 0..7
    const int lane = tid & 63;
    const int wm = w >> 2;           // 0..1
    const int wn = w & 3;            // 0..3
    const int m0 = blockIdx.y * 128;
    const int n0 = blockIdx.x * 128;

    const int r4 = lane >> 2;
    const int csw = (lane & 3) ^ ((r4 >> 1) & 3);
    const int gk = csw * 8;
    const int l31 = lane & 31;
    const int khalf = lane >> 5;
    const int rsw = (l31 >> 1) & 3;

    floatx16 acc[2] = {};

    for (int k0 = 0; k0 < KP; k0 += 64) {
#pragma unroll
        for (int seg = 0; seg < 2; ++seg) {
            const unsigned short* Asrc = A + seg * KP;
            const unsigned short* Bsrc = Bm + seg * KP;
#pragma unroll
            for (int t = 0; t < 2; ++t) {
                async_ld16(Asrc + (size_t)(m0 + w * 16 + r4) * (2 * KP) + k0 + t * 32 + gk,
                           &As[seg * 8192 + t * 4096 + w * 512]);
                async_ld16(Bsrc + (size_t)(n0 + w * 16 + r4) * (2 * KP) + k0 + t * 32 + gk,
                           &Bs[seg * 8192 + t * 4096 + w * 512]);
            }
        }
        __syncthreads();

#pragma unroll
        for (int t = 0; t < 2; ++t) {
#pragma unroll
            for (int kk = 0; kk < 2; ++kk) {
                const int pos = ((kk * 2 + khalf) ^ rsw) << 3;
                shortx8 ah[2], al[2], bh, bl;
#pragma unroll
                for (int i = 0; i < 2; ++i) {
                    int row = wm * 64 + i * 32 + l31;
                    ah[i] = *(const shortx8*)&As[t * 4096 + row * 32 + pos];
                    al[i] = *(const shortx8*)&As[8192 + t * 4096 + row * 32 + pos];
                }
                {
                    int col = wn * 32 + l31;
                    bh = *(const shortx8*)&Bs[t * 4096 + col * 32 + pos];
                    bl = *(const shortx8*)&Bs[8192 + t * 4096 + col * 32 + pos];
                }
#pragma unroll
                for (int i = 0; i < 2; ++i) {
                    acc[i] = __builtin_amdgcn_mfma_f32_32x32x16_bf16(ah[i], bh, acc[i], 0, 0, 0);
                    acc[i] = __builtin_amdgcn_mfma_f32_32x32x16_bf16(ah[i], bl, acc[i], 0, 0, 0);
                    acc[i] = __builtin_amdgcn_mfma_f32_32x32x16_bf16(al[i], bh, acc[i], 0, 0, 0);
                }
            }
        }
        __syncthreads();
    }

    // epilogue: col = lane&31, row = (reg&3)+8*(reg>>2)+4*(lane>>5) (m74/m101)
#pragma unroll
    for (int i = 0; i < 2; ++i) {
        int col = n0 + wn * 32 + l31;
#pragma unroll
        for (int r = 0; r < 16; ++r) {
            int row = m0 + wm * 64 + i * 32 + (r & 3) + 8 * (r >> 2) + 4 * khalf;
            C[(size_t)row * ldc + col] = acc[i][r];
        }
    }
}

// ---------------------------------------------------------------------------
// dt_proj GEMM (R19): BN=64, KP=64, single staging round, fused bias+softplus.
// ---------------------------------------------------------------------------
template <int BN, int KP>
__global__ __launch_bounds__(256) void gemm_bf16_sp(
    const unsigned short* __restrict__ A,
    const unsigned short* __restrict__ Bm,
    float* __restrict__ C, int ldc, const float* __restrict__ bias)
{
    constexpr int TN32 = BN / 64;
    __shared__ unsigned short As[2 * 8192];
    __shared__ unsigned short Bs[2 * BN * 64];

    const int tid = threadIdx.x;
    const int w = tid >> 6;
    const int lane = tid & 63;
    const int wm = w >> 1, wn = w & 1;
    const int m0 = blockIdx.y * 128;
    const int n0 = blockIdx.x * BN;

    const int r4 = lane >> 2;
    const int csw = (lane & 3) ^ ((r4 >> 1) & 3);
    const int gk = csw * 8;
    const int l31 = lane & 31;
    const int khalf = lane >> 5;
    const int rsw = (l31 >> 1) & 3;

    floatx16 acc[2][TN32] = {};

    for (int k0 = 0; k0 < KP; k0 += 64) {
#pragma unroll
        for (int seg = 0; seg < 2; ++seg) {
            const unsigned short* Asrc = A + seg * KP;
            const unsigned short* Bsrc = Bm + seg * KP;
#pragma unroll
            for (int t = 0; t < 2; ++t) {
#pragma unroll
                for (int jj = 0; jj < 2; ++jj) {
                    int j = w + jj * 4;
                    async_ld16(Asrc + (size_t)(m0 + j * 16 + r4) * (2 * KP) + k0 + t * 32 + gk,
                               &As[seg * 8192 + t * 4096 + j * 512]);
                }
#pragma unroll
                for (int jj = 0; jj < BN / 64; ++jj) {
                    int j = w + jj * 4;
                    async_ld16(Bsrc + (size_t)(n0 + j * 16 + r4) * (2 * KP) + k0 + t * 32 + gk,
                               &Bs[seg * BN * 64 + t * BN * 32 + j * 512]);
                }
            }
        }
        __syncthreads();

#pragma unroll
        for (int t = 0; t < 2; ++t) {
#pragma unroll
            for (int kk = 0; kk < 2; ++kk) {
                const int pos = ((kk * 2 + khalf) ^ rsw) << 3;
                shortx8 ah[2], al[2], bh[TN32], bl[TN32];
#pragma unroll
                for (int i = 0; i < 2; ++i) {
                    int row = wm * 64 + i * 32 + l31;
                    ah[i] = *(const shortx8*)&As[t * 4096 + row * 32 + pos];
                    al[i] = *(const shortx8*)&As[8192 + t * 4096 + row * 32 + pos];
                }
#pragma unroll
                for (int j = 0; j < TN32; ++j) {
                    int col = wn * (BN / 2) + j * 32 + l31;
                    bh[j] = *(const shortx8*)&Bs[t * BN * 32 + col * 32 + pos];
                    bl[j] = *(const shortx8*)&Bs[BN * 64 + t * BN * 32 + col * 32 + pos];
                }
#pragma unroll
                for (int i = 0; i < 2; ++i)
#pragma unroll
                    for (int j = 0; j < TN32; ++j) {
                        acc[i][j] = __builtin_amdgcn_mfma_f32_32x32x16_bf16(ah[i], bh[j], acc[i][j], 0, 0, 0);
                        acc[i][j] = __builtin_amdgcn_mfma_f32_32x32x16_bf16(ah[i], bl[j], acc[i][j], 0, 0, 0);
                        acc[i][j] = __builtin_amdgcn_mfma_f32_32x32x16_bf16(al[i], bh[j], acc[i][j], 0, 0, 0);
                    }
            }
        }
        __syncthreads();
    }

#pragma unroll
    for (int i = 0; i < 2; ++i) {
#pragma unroll
        for (int j = 0; j < TN32; ++j) {
            int col = n0 + wn * (BN / 2) + j * 32 + l31;
            float bz = bias[col];
#pragma unroll
            for (int r = 0; r < 16; ++r) {
                int row = m0 + wm * 64 + i * 32 + (r & 3) + 8 * (r >> 2) + 4 * khalf;
                C[(size_t)row * ldc + col] = softplusf(acc[i][j][r] + bz);
            }
        }
    }
}

// ---------------------------------------------------------------------------
// fp32 -> 2-segment split-bf16: row = [hi (K) | lo (K)], stride 2K (out_proj)
// ---------------------------------------------------------------------------
__global__ __launch_bounds__(256) void split2_kernel(
    const float* __restrict__ src, unsigned short* __restrict__ dst, int K)
{
    int i = blockIdx.x * 256 + threadIdx.x;
    int m = i / K;
    int k = i - m * K;
    float a = src[i];
    __hip_bfloat16 h = __float2bfloat16(a);
    __hip_bfloat16 l = __float2bfloat16(a - __bfloat162float(h));
    unsigned short* row = dst + (size_t)m * 2 * K;
    row[k] = *(unsigned short*)&h;
    row[K + k] = *(unsigned short*)&l;
}

// ---------------------------------------------------------------------------
// x_proj split-K partial GEMM + reduce (BK=64, R18)
// ---------------------------------------------------------------------------
__global__ __launch_bounds__(256) void xproj_splitk(
    const float* __restrict__ u, const float* __restrict__ Wx,
    float* __restrict__ Cp)
{
    __shared__ float As[64][68];     // [k][row]
    __shared__ float Bs[64][100];    // [k][row]

    const int tid = threadIdx.x;
    const int ks = blockIdx.x;
    const int m0 = blockIdx.y * 64;
    const int tx = tid & 15;
    const int ty = tid >> 4;

    float acc[4][6] = {};

    for (int k0 = ks * KC; k0 < (ks + 1) * KC; k0 += 64) {
        for (int idx = tid * 4; idx < 64 * 64; idx += 1024) {
            int row = idx >> 6, kk = idx & 63;
            float4 v = *(const float4*)&u[(size_t)(m0 + row) * DINNER + k0 + kk];
            As[kk + 0][row] = v.x;
            As[kk + 1][row] = v.y;
            As[kk + 2][row] = v.z;
            As[kk + 3][row] = v.w;
        }
        for (int idx = tid * 4; idx < 96 * 64; idx += 1024) {
            int row = idx >> 6, kk = idx & 63;
            float4 v = *(const float4*)&Wx[(size_t)row * DINNER + k0 + kk];
            Bs[kk + 0][row] = v.x;
            Bs[kk + 1][row] = v.y;
            Bs[kk + 2][row] = v.z;
            Bs[kk + 3][row] = v.w;
        }
        __syncthreads();

#pragma unroll 8
        for (int k = 0; k < 64; ++k) {
            float a[4], b[6];
#pragma unroll
            for (int i = 0; i < 4; ++i) a[i] = As[k][ty * 4 + i];
#pragma unroll
            for (int j = 0; j < 6; ++j) b[j] = Bs[k][tx * 6 + j];
#pragma unroll
            for (int i = 0; i < 4; ++i)
#pragma unroll
                for (int j = 0; j < 6; ++j) acc[i][j] = fmaf(a[i], b[j], acc[i][j]);
        }
        __syncthreads();
    }

    float* outp = Cp + ((size_t)ks * M_ROWS + m0) * 96;
#pragma unroll
    for (int i = 0; i < 4; ++i)
#pragma unroll
        for (int j = 0; j < 6; ++j)
            outp[(ty * 4 + i) * 96 + tx * 6 + j] = acc[i][j];
}

__global__ __launch_bounds__(256) void xproj_reduce(
    const float* __restrict__ Cp, float* __restrict__ xdbl)
{
    int i = blockIdx.x * 256 + threadIdx.x;
    float s = 0.f;
#pragma unroll
    for (int c = 0; c < KSPLIT; ++c)
        s += Cp[(size_t)c * M_ROWS * 96 + i];
    xdbl[i] = s;
}

// ---------------------------------------------------------------------------
// conv + silu, float4 over channels
// ---------------------------------------------------------------------------
__global__ __launch_bounds__(256) void conv_silu_v4(
    const float* __restrict__ xz, const float* __restrict__ cw,
    const float* __restrict__ cb, float* __restrict__ u)
{
    int i = blockIdx.x * 256 + threadIdx.x;      // over M_ROWS * 512
    int dq = (i & 511) << 2;
    int bl = i >> 9;
    int b = bl >> 11;
    int l = bl & 2047;

    float4 W0 = *(const float4*)&cw[(dq + 0) * 4];
    float4 W1 = *(const float4*)&cw[(dq + 1) * 4];
    float4 W2 = *(const float4*)&cw[(dq + 2) * 4];
    float4 W3 = *(const float4*)&cw[(dq + 3) * 4];
    float4 acc = *(const float4*)&cb[dq];

#pragma unroll
    for (int k = 0; k < 4; ++k) {
        int ls = l + k - 3;
        if (ls >= 0) {
            float4 v = *(const float4*)&xz[((size_t)(b << 11) + ls) * 4096 + dq];
            acc.x = fmaf(v.x, ((const float*)&W0)[k], acc.x);
            acc.y = fmaf(v.y, ((const float*)&W1)[k], acc.y);
            acc.z = fmaf(v.z, ((const float*)&W2)[k], acc.z);
            acc.w = fmaf(v.w, ((const float*)&W3)[k], acc.w);
        }
    }
    float4 r = make_float4(siluf(acc.x), siluf(acc.y), siluf(acc.z), siluf(acc.w));
    *(float4*)&u[(size_t)bl * DINNER + dq] = r;
}

// ---------------------------------------------------------------------------
// Chunked selective scan (3 passes). PASS3 fuses gate + split-bf16 y2
// (linear 2-seg layout [4096][hi 2048 | lo 2048]).
// ---------------------------------------------------------------------------
template <bool PASS3>
__global__ __launch_bounds__(256) void scan_chunk(
    const float* __restrict__ dbuf, const float* __restrict__ ubuf,
    const float* __restrict__ xdbl, const float* __restrict__ A_log,
    const float* __restrict__ Dv,
    float* __restrict__ Pbuf, float* __restrict__ Sbuf,
    const float* __restrict__ xz, unsigned short* __restrict__ y2)
{
    __shared__ float sd[16][CPB];
    __shared__ float su[16][CPB];
    __shared__ float sB[16][DSTATE];
    __shared__ float sC[16][DSTATE];

    const int tid = threadIdx.x;
    const int c    = blockIdx.x % CH;
    const int dblk = (blockIdx.x / CH) % (DINNER / CPB);
    const int b    = blockIdx.x / (CH * (DINNER / CPB));
    const int d0 = dblk * CPB;
    const int dg = tid >> 2;
    const int q  = tid & 3;
    const int d  = d0 + dg;
    const size_t base_bl = (size_t)b * L_SZ + (size_t)c * CLEN;

    float Ac[4], h[4];
    float sdl = 0.f;
#pragma unroll
    for (int j = 0; j < 4; ++j)
        Ac[j] = -expf(A_log[d * DSTATE + 4 * q + j]);
    const size_t psoff = (((size_t)b * CH + c) * DINNER + d0) * DSTATE + (size_t)tid * 4;
    if (PASS3) {
        float4 h0 = *(const float4*)&Sbuf[psoff];
        h[0] = h0.x; h[1] = h0.y; h[2] = h0.z; h[3] = h0.w;
    } else {
        h[0] = h[1] = h[2] = h[3] = 0.f;
    }
    const float Dd = PASS3 ? Dv[d] : 0.f;

    const int ls = tid >> 4;
    const int g4 = (tid & 15) * 4;
    const int ln = tid & 15;

    float4 r_d = *(const float4*)&dbuf[(base_bl + ls) * DINNER + d0 + g4];
    float4 r_u = *(const float4*)&ubuf[(base_bl + ls) * DINNER + d0 + g4];
    float r_B = xdbl[(base_bl + ls) * 96 + 64 + ln];
    float r_C = xdbl[(base_bl + ls) * 96 + 80 + ln];

    for (int l0 = 0; l0 < CLEN; l0 += 16) {
        __syncthreads();
        *(float4*)&sd[ls][g4] = r_d;
        *(float4*)&su[ls][g4] = r_u;
        sB[ls][ln] = r_B;
        sC[ls][ln] = r_C;
        __syncthreads();

        if (l0 + 16 < CLEN) {
            r_d = *(const float4*)&dbuf[(base_bl + l0 + 16 + ls) * DINNER + d0 + g4];
            r_u = *(const float4*)&ubuf[(base_bl + l0 + 16 + ls) * DINNER + d0 + g4];
            r_B = xdbl[(base_bl + l0 + 16 + ls) * 96 + 64 + ln];
            r_C = xdbl[(base_bl + l0 + 16 + ls) * 96 + 80 + ln];
        }

#pragma unroll
        for (int s = 0; s < 16; ++s) {
            float dl = sd[s][dg];
            float ul = su[s][dg];
            float4 Bv = *(float4*)&sB[s][4 * q];
            float dbu = dl * ul;
            float dA0 = expf(dl * Ac[0]);
            float dA1 = expf(dl * Ac[1]);
            float dA2 = expf(dl * Ac[2]);
            float dA3 = expf(dl * Ac[3]);
            h[0] = fmaf(dA0, h[0], dbu * Bv.x);
            h[1] = fmaf(dA1, h[1], dbu * Bv.y);
            h[2] = fmaf(dA2, h[2], dbu * Bv.z);
            h[3] = fmaf(dA3, h[3], dbu * Bv.w);
            if (!PASS3) {
                sdl += dl;
            } else {
                float4 Cv = *(float4*)&sC[s][4 * q];
                float y = h[0] * Cv.x + h[1] * Cv.y + h[2] * Cv.z + h[3] * Cv.w;
                y += __shfl_xor(y, 1);
                y += __shfl_xor(y, 2);
                if (q == 0) su[s][dg] = fmaf(ul, Dd, y);
            }
        }

        if (PASS3) {
            __syncthreads();
            size_t row = base_bl + l0 + ls;
            float4 yv = *(float4*)&su[ls][g4];
            float4 rv = *(const float4*)&xz[row * 4096 + 2048 + d0 + g4];
            float a0 = yv.x * siluf(rv.x);
            float a1 = yv.y * siluf(rv.y);
            float a2 = yv.z * siluf(rv.z);
            float a3 = yv.w * siluf(rv.w);
            __hip_bfloat16 h0 = __float2bfloat16(a0), h1 = __float2bfloat16(a1);
            __hip_bfloat16 h2 = __float2bfloat16(a2), h3 = __float2bfloat16(a3);
            __hip_bfloat16 l0b = __float2bfloat16(a0 - __bfloat162float(h0));
            __hip_bfloat16 l1b = __float2bfloat16(a1 - __bfloat162float(h1));
            __hip_bfloat16 l2b = __float2bfloat16(a2 - __bfloat162float(h2));
            __hip_bfloat16 l3b = __float2bfloat16(a3 - __bfloat162float(h3));
            ushort4 hv = make_ushort4(*(unsigned short*)&h0, *(unsigned short*)&h1,
                                      *(unsigned short*)&h2, *(unsigned short*)&h3);
            ushort4 lv = make_ushort4(*(unsigned short*)&l0b, *(unsigned short*)&l1b,
                                      *(unsigned short*)&l2b, *(unsigned short*)&l3b);
            unsigned short* yrow = y2 + row * 2 * DINNER + d0 + g4;
            *(ushort4*)&yrow[0] = hv;
            *(ushort4*)&yrow[DINNER] = lv;
        }
    }

    if (!PASS3) {
        *(float4*)&Pbuf[psoff] = make_float4(expf(Ac[0] * sdl), expf(Ac[1] * sdl),
                                             expf(Ac[2] * sdl), expf(Ac[3] * sdl));
        *(float4*)&Sbuf[psoff] = make_float4(h[0], h[1], h[2], h[3]);
    }
}

__global__ __launch_bounds__(256) void scan_combine(
    const float* __restrict__ Pbuf, float* __restrict__ Sbuf)
{
    int t = blockIdx.x * 256 + threadIdx.x;
    int b = t >> 15;
    int rem = t & 32767;
    size_t base = (size_t)b * CH * DINNER * DSTATE + rem;
    float H = 0.f;
#pragma unroll 4
    for (int c = 0; c < CH; ++c) {
        size_t off = base + (size_t)c * DINNER * DSTATE;
        float S = Sbuf[off];
        float P = Pbuf[off];
        Sbuf[off] = H;
        H = fmaf(P, H, S);
    }
}

// ---------------------------------------------------------------------------
extern "C" void kernel_launch(void* const* d_in, const int* in_sizes, int n_in,
                              void* d_out, int out_size, void* d_ws, size_t ws_size,
                              hipStream_t stream)
{
    const float* x          = (const float*)d_in[0];
    const float* in_proj_w  = (const float*)d_in[1];
    const float* conv_w     = (const float*)d_in[2];
    const float* conv_b     = (const float*)d_in[3];
    const float* x_proj_w   = (const float*)d_in[4];
    const float* dt_proj_w  = (const float*)d_in[5];
    const float* dt_proj_b  = (const float*)d_in[6];
    const float* A_log      = (const float*)d_in[7];
    const float* Dv         = (const float*)d_in[8];
    const float* out_proj_w = (const float*)d_in[9];
    float* out = (float*)d_out;

    // workspace layout (bytes):
    char* w = (char*)d_ws;
    float* xz   = (float*)(w);                       // 64 MB
    float* u    = (float*)(w + 67108864);            // 32 MB (written step 3)
    float* dbuf = (float*)(w + 100663296);           // 32 MB (written step 5)
    float* xdbl = (float*)(w + 134217728);           // 1.5 MB
    float* Pbuf = (float*)(w + 135790592);           // 8 MB (dead after combine)
    float* Sbuf = (float*)(w + 144179200);           // 8 MB (ends 152567808)
    unsigned short* y2  = (unsigned short*)(w + 152567808);   // 32 MB [4096][4096] 2-seg
    unsigned short* w2b = (unsigned short*)(w + 135790592);   // 8 MB over Pbuf (dead at 7)
    float* Cp = (float*)(w + 152567808);             // xproj partials (dead at 4, pre-y2)
    // dt_proj 2-seg inputs; over dead Cp region, consumed before pass3 writes y2
    unsigned short* dt2  = (unsigned short*)(w + 152567808);            // 1 MB
    unsigned short* wdt2 = (unsigned short*)(w + 152567808 + 1048576);  // 0.5 MB
    // dedup 2-seg panels for in_proj; ALIAS u / dbuf (dead after step 2)
    unsigned short* x2p  = (unsigned short*)(w + 67108864);   // 16 MB over u
    unsigned short* w2ap = (unsigned short*)(w + 100663296);  // 16 MB over dbuf

    // 1) split x / in_proj_w -> dedup 2-seg panels (line-read remap, 512 blk)
    split3_kernel<4096, 1024><<<512, 256, 0, stream>>>(x, x2p);
    split3_kernel<4096, 1024><<<512, 256, 0, stream>>>(in_proj_w, w2ap);
    // 2) in_proj: 8-phase GEMM, KT=48, SEGT=16, NB=16 (R16-exact, control)
    gemm_8ph<48, 16, 16, 4096><<<256, 512, 0, stream>>>(x2p, w2ap, xz);
    // 3) conv + silu -> u (overwrites x2p, dead)
    conv_silu_v4<<<(M_ROWS * 512) / 256, 256, 0, stream>>>(xz, conv_w, conv_b, u);
    // 4) x_proj via split-K (BK=64); Cp dead after reduce
    {
        dim3 g(KSPLIT, M_ROWS / 64);
        xproj_splitk<<<g, 256, 0, stream>>>(u, x_proj_w, Cp);
        xproj_reduce<<<(M_ROWS * 96) / 256, 256, 0, stream>>>(Cp, xdbl);
    }
    // 5) dt_proj on MFMA (R19): split inputs, GEMM + fused bias/softplus
    {
        split2k_kernel<96><<<1024, 256, 0, stream>>>(xdbl, dt2);
        split2k_kernel<64><<<512, 256, 0, stream>>>(dt_proj_w, wdt2);
        dim3 g(DINNER / 64, M_ROWS / 128);
        gemm_bf16_sp<64, 64><<<g, 256, 0, stream>>>(dt2, wdt2, dbuf, DINNER, dt_proj_b);
    }
    // 6) chunked selective scan; pass3 fuses gate + linear 2-seg split into y2
    {
        const int nblk = B_SZ * (DINNER / CPB) * CH;
        scan_chunk<false><<<nblk, 256, 0, stream>>>(dbuf, u, xdbl, A_log, Dv, Pbuf, Sbuf, nullptr, nullptr);
        scan_combine<<<B_SZ * DINNER * DSTATE / 256, 256, 0, stream>>>(Pbuf, Sbuf);
        scan_chunk<true><<<nblk, 256, 0, stream>>>(dbuf, u, xdbl, A_log, Dv, nullptr, Sbuf, xz, y2);
    }
    // 7) split out_proj_w (2-seg linear; Pbuf dead after combine)
    split2_kernel<<<(DMODEL * DINNER) / 256, 256, 0, stream>>>(out_proj_w, w2b, DINNER);
    // 8) out_proj via 128x128-tile 512-thread MFMA GEMM (2 waves/SIMD)
    {
        dim3 g(DMODEL / 128, M_ROWS / 128);
        gemm_bf16_128x128<2048><<<g, 512, 0, stream>>>(y2, w2b, out, 1024);
    }
}

// Round 12
// 448.105 us; speedup vs baseline: 1.1385x; 1.1167x over previous
//
#include <hip/hip_runtime.h>
#include <hip/hip_bf16.h>
#include <math.h>

#define B_SZ 2
#define L_SZ 2048
#define DMODEL 1024
#define DINNER 2048
#define DSTATE 16
#define DTRANK 64
#define M_ROWS (B_SZ * L_SZ)   // 4096

#define CH 32
#define CLEN (L_SZ / CH)
#define CPB 64

#define KSPLIT 8
#define KC (DINNER / KSPLIT)   // 256

typedef short shortx8 __attribute__((ext_vector_type(8)));
typedef float floatx4 __attribute__((ext_vector_type(4)));
typedef float floatx16 __attribute__((ext_vector_type(16)));

// R21: fast transcendentals. Harness compiles without -ffast-math, so expf
// is the precise OCML path (~6-10 instrs). __expf = v_mul + v_exp_f32
// (~1e-7 rel err, 3 decades below our 1.22e-4 bf16-split absmax floor).
// scan_chunk runs 4 exps/thread/timestep x 64 steps x 2 passes -- the
// dominant VALU cost of the scan tier (R9-style latency/VALU-bound kernels).
__device__ __forceinline__ float fexpf(float x) { return __expf(x); }

__device__ __forceinline__ float softplusf(float x) {
    return fmaxf(x, 0.f) + log1pf(fexpf(-fabsf(x)));
}
__device__ __forceinline__ float siluf(float x) {
    return x * (1.f / (1.f + fexpf(-x)));
}

__device__ __forceinline__ void async_ld16(const void* g, void* l) {
    __builtin_amdgcn_global_load_lds(
        (__attribute__((address_space(1))) void*)(unsigned long long)g,
        (__attribute__((address_space(3))) void*)(unsigned int)(unsigned long long)l,
        16, 0, 0);
}

// ---------------------------------------------------------------------------
// fp32 [ROWS][KSRC] -> dedup 2-seg ([h|l]) panelized bf16 in LDS-image order.
// Each thread: one 128B line (32 floats = 4 k8-groups) of one row. (R20)
// ---------------------------------------------------------------------------
template <int ROWS, int KSRC>
__global__ __launch_bounds__(256) void split3_kernel(
    const float* __restrict__ src, unsigned short* __restrict__ dst)
{
    constexpr int SEGT = KSRC / 64;
    int i = blockIdx.x * 256 + threadIdx.x;   // ROWS x (KSRC/32) line-groups
    int row = i & (ROWS - 1);
    int g = i / ROWS;                         // 0..KSRC/32-1
    const float* s = src + (size_t)row * KSRC + g * 32;
    int tloc = g >> 1;
    int sh = g & 1;
    size_t base = ((size_t)(row >> 8) * 4 * SEGT + tloc * 2 + sh) * 8192
                + (size_t)(row & 255) * 8;
#pragma unroll
    for (int q = 0; q < 4; ++q) {
        float4 v0 = *(const float4*)(s + q * 8);
        float4 v1 = *(const float4*)(s + q * 8 + 4);
        float fs[8] = {v0.x, v0.y, v0.z, v0.w, v1.x, v1.y, v1.z, v1.w};
        shortx8 hv, lv;
#pragma unroll
        for (int j = 0; j < 8; ++j) {
            __hip_bfloat16 h = __float2bfloat16(fs[j]);
            __hip_bfloat16 l = __float2bfloat16(fs[j] - __bfloat162float(h));
            hv[j] = *(unsigned short*)&h;
            lv[j] = *(unsigned short*)&l;
        }
        size_t off = base + (size_t)q * 2048;
        *(shortx8*)&dst[off] = hv;
        *(shortx8*)&dst[off + (size_t)2 * SEGT * 8192] = lv;
    }
}

// fp32 [rows][LDSRC] (first 64 cols) -> 2-seg bf16 rows [hi 64 | lo 64]
template <int LDSRC>
__global__ __launch_bounds__(256) void split2k_kernel(
    const float* __restrict__ src, unsigned short* __restrict__ dst)
{
    int i = blockIdx.x * 256 + threadIdx.x;   // rows * 64
    int m = i >> 6, k = i & 63;
    float a = src[(size_t)m * LDSRC + k];
    __hip_bfloat16 h = __float2bfloat16(a);
    __hip_bfloat16 l = __float2bfloat16(a - __bfloat162float(h));
    unsigned short* row = dst + (size_t)m * 128;
    row[k] = *(unsigned short*)&h;
    row[64 + k] = *(unsigned short*)&l;
}

// ---------------------------------------------------------------------------
// 8-phase 256x256 pipelined bf16 GEMM over dedup-2-seg panels (R14/R16
// schedule -- verified 92.4-96us @ 45-47% MfmaUtil across 6 rounds/5 boxes).
// ---------------------------------------------------------------------------
template <int KT, int SEGT, int NB, int LDC>
__global__ __launch_bounds__(512, 2) void gemm_8ph(
    const unsigned short* __restrict__ Ap,
    const unsigned short* __restrict__ Bp,
    float* __restrict__ C)
{
    __shared__ unsigned short lds[65536];   // 128KB

    const int tid = threadIdx.x;
    const int lane = tid & 63;
    const int w = tid >> 6;                 // 0..7
    const int wm = w >> 2, wn = w & 3;      // 2 x 4
    const int l15 = lane & 15, l4 = lane >> 4;

    int id = blockIdx.x;
    id = (id & 7) * 32 + (id >> 3);         // bijective XCD swizzle (256 blocks)
    const int bm = id / NB;
    const int bn = id % NB;

    const unsigned short* ga = Ap + (size_t)bm * 4 * SEGT * 8192;
    const unsigned short* gb = Bp + (size_t)bn * 4 * SEGT * 8192;

    const int rA = (l4 * 256 + wm * 128 + l15) * 8;
    const int rB = (l4 * 256 + wn * 64 + l15) * 8;

    floatx4 acc[8][4] = {};
    shortx8 bfr[4];

    auto STAGE = [&](int vt, int ab, int s) {
        int Tv = vt < KT ? vt : KT - 1;    // virtual tiles clamp (counts stay exact)
        int Tm = ab ? (Tv >= SEGT ? Tv - SEGT : Tv)            // B: [h,h,l]
                    : (Tv >= 2 * SEGT ? Tv - 2 * SEGT : Tv);   // A: [h,l,h]
        const unsigned short* src = (ab ? gb : ga) + ((size_t)Tm * 2 + s) * 8192 + tid * 8;
        unsigned short* dst = (unsigned short*)lds + (vt & 1) * 32768 + ab * 16384 + s * 8192 + tid * 8;
        async_ld16(src, dst);
        async_ld16(src + 4096, dst + 4096);
    };

#define MFMA16(MH)                                                                             \
    acc[(MH)*4+0][0] = __builtin_amdgcn_mfma_f32_16x16x32_bf16(af0, bfr[0], acc[(MH)*4+0][0], 0,0,0); \
    acc[(MH)*4+0][1] = __builtin_amdgcn_mfma_f32_16x16x32_bf16(af0, bfr[1], acc[(MH)*4+0][1], 0,0,0); \
    acc[(MH)*4+0][2] = __builtin_amdgcn_mfma_f32_16x16x32_bf16(af0, bfr[2], acc[(MH)*4+0][2], 0,0,0); \
    acc[(MH)*4+0][3] = __builtin_amdgcn_mfma_f32_16x16x32_bf16(af0, bfr[3], acc[(MH)*4+0][3], 0,0,0); \
    acc[(MH)*4+1][0] = __builtin_amdgcn_mfma_f32_16x16x32_bf16(af1, bfr[0], acc[(MH)*4+1][0], 0,0,0); \
    acc[(MH)*4+1][1] = __builtin_amdgcn_mfma_f32_16x16x32_bf16(af1, bfr[1], acc[(MH)*4+1][1], 0,0,0); \
    acc[(MH)*4+1][2] = __builtin_amdgcn_mfma_f32_16x16x32_bf16(af1, bfr[2], acc[(MH)*4+1][2], 0,0,0); \
    acc[(MH)*4+1][3] = __builtin_amdgcn_mfma_f32_16x16x32_bf16(af1, bfr[3], acc[(MH)*4+1][3], 0,0,0); \
    acc[(MH)*4+2][0] = __builtin_amdgcn_mfma_f32_16x16x32_bf16(af2, bfr[0], acc[(MH)*4+2][0], 0,0,0); \
    acc[(MH)*4+2][1] = __builtin_amdgcn_mfma_f32_16x16x32_bf16(af2, bfr[1], acc[(MH)*4+2][1], 0,0,0); \
    acc[(MH)*4+2][2] = __builtin_amdgcn_mfma_f32_16x16x32_bf16(af2, bfr[2], acc[(MH)*4+2][2], 0,0,0); \
    acc[(MH)*4+2][3] = __builtin_amdgcn_mfma_f32_16x16x32_bf16(af2, bfr[3], acc[(MH)*4+2][3], 0,0,0); \
    acc[(MH)*4+3][0] = __builtin_amdgcn_mfma_f32_16x16x32_bf16(af3, bfr[0], acc[(MH)*4+3][0], 0,0,0); \
    acc[(MH)*4+3][1] = __builtin_amdgcn_mfma_f32_16x16x32_bf16(af3, bfr[1], acc[(MH)*4+3][1], 0,0,0); \
    acc[(MH)*4+3][2] = __builtin_amdgcn_mfma_f32_16x16x32_bf16(af3, bfr[2], acc[(MH)*4+3][2], 0,0,0); \
    acc[(MH)*4+3][3] = __builtin_amdgcn_mfma_f32_16x16x32_bf16(af3, bfr[3], acc[(MH)*4+3][3], 0,0,0);

// VM: 1 = counted s_waitcnt vmcnt(4) (phases 4 and 8 only; never 0 mid-loop)
#define PHASE(SLOT, S, MH, SVT, SAB, SS, VM)                                   \
    {                                                                          \
        const unsigned short* Ab = &lds[(SLOT)*32768 + (S)*8192] + rA;         \
        shortx8 af0 = *(const shortx8*)&Ab[((MH)*4 + 0) * 128];                \
        shortx8 af1 = *(const shortx8*)&Ab[((MH)*4 + 1) * 128];                \
        shortx8 af2 = *(const shortx8*)&Ab[((MH)*4 + 2) * 128];                \
        shortx8 af3 = *(const shortx8*)&Ab[((MH)*4 + 3) * 128];                \
        if ((MH) == 0) {                                                       \
            const unsigned short* Bb = &lds[(SLOT)*32768 + 16384 + (S)*8192] + rB; \
            bfr[0] = *(const shortx8*)&Bb[0];                                  \
            bfr[1] = *(const shortx8*)&Bb[128];                                \
            bfr[2] = *(const shortx8*)&Bb[256];                                \
            bfr[3] = *(const shortx8*)&Bb[384];                                \
        }                                                                      \
        STAGE(SVT, SAB, SS);                                                   \
        __builtin_amdgcn_s_barrier();                                          \
        asm volatile("s_waitcnt lgkmcnt(0)" ::: "memory");                     \
        __builtin_amdgcn_s_setprio(1);                                         \
        MFMA16(MH)                                                             \
        __builtin_amdgcn_s_setprio(0);                                         \
        if (VM) { asm volatile("s_waitcnt vmcnt(4)" ::: "memory"); }           \
        __builtin_amdgcn_s_barrier();                                          \
    }

    STAGE(0, 0, 0); STAGE(0, 1, 0); STAGE(0, 0, 1); STAGE(0, 1, 1);
    STAGE(1, 0, 0); STAGE(1, 1, 0);
    asm volatile("s_waitcnt vmcnt(4)" ::: "memory");
    __builtin_amdgcn_s_barrier();

#pragma unroll 1
    for (int i = 0; i < KT / 2; ++i) {
        const int t2 = 2 * i;
        PHASE(0, 0, 0, t2 + 1, 0, 1, 0)
        PHASE(0, 0, 1, t2 + 1, 1, 1, 0)
        PHASE(0, 1, 0, t2 + 2, 0, 0, 0)
        PHASE(0, 1, 1, t2 + 2, 1, 0, 1)   // vmcnt(4): all of t(2i+1) landed
        PHASE(1, 0, 0, t2 + 2, 0, 1, 0)
        PHASE(1, 0, 1, t2 + 2, 1, 1, 0)
        PHASE(1, 1, 0, t2 + 3, 0, 0, 0)
        PHASE(1, 1, 1, t2 + 3, 1, 0, 1)   // vmcnt(4): all of t(2i+2) landed
    }

#undef PHASE
#undef MFMA16

    // epilogue: C/D 16x16: col = lane&15, row = (lane>>4)*4 + reg (m89)
    const int c0 = bn * 256 + wn * 64;
    const int r0 = bm * 256 + wm * 128;
#pragma unroll
    for (int fi = 0; fi < 8; ++fi) {
#pragma unroll
        for (int fj = 0; fj < 4; ++fj) {
            int col = c0 + fj * 16 + l15;
            int rowb = r0 + fi * 16 + l4 * 4;
#pragma unroll
            for (int ri = 0; ri < 4; ++ri)
                C[(size_t)(rowb + ri) * LDC + col] = acc[fi][fj][ri];
        }
    }
}

// ---------------------------------------------------------------------------
// out_proj: 128x128-tile, 512-thread (8-wave) bf16 GEMM, R8 sync structure.
// (R20-verified: below top-5 cutoff vs 109us for the old BN=64 path.)
// ---------------------------------------------------------------------------
template <int KP>
__global__ __launch_bounds__(512) void gemm_bf16_128x128(
    const unsigned short* __restrict__ A,
    const unsigned short* __restrict__ Bm,
    float* __restrict__ C, int ldc)
{
    __shared__ unsigned short As[2 * 8192];    // [seg][t][8 j][512]
    __shared__ unsigned short Bs[2 * 8192];

    const int tid = threadIdx.x;
    const int w = tid >> 6;          // 0..7
    const int lane = tid & 63;
    const int wm = w >> 2;           // 0..1
    const int wn = w & 3;            // 0..3
    const int m0 = blockIdx.y * 128;
    const int n0 = blockIdx.x * 128;

    const int r4 = lane >> 2;
    const int csw = (lane & 3) ^ ((r4 >> 1) & 3);
    const int gk = csw * 8;
    const int l31 = lane & 31;
    const int khalf = lane >> 5;
    const int rsw = (l31 >> 1) & 3;

    floatx16 acc[2] = {};

    for (int k0 = 0; k0 < KP; k0 += 64) {
#pragma unroll
        for (int seg = 0; seg < 2; ++seg) {
            const unsigned short* Asrc = A + seg * KP;
            const unsigned short* Bsrc = Bm + seg * KP;
#pragma unroll
            for (int t = 0; t < 2; ++t) {
                async_ld16(Asrc + (size_t)(m0 + w * 16 + r4) * (2 * KP) + k0 + t * 32 + gk,
                           &As[seg * 8192 + t * 4096 + w * 512]);
                async_ld16(Bsrc + (size_t)(n0 + w * 16 + r4) * (2 * KP) + k0 + t * 32 + gk,
                           &Bs[seg * 8192 + t * 4096 + w * 512]);
            }
        }
        __syncthreads();

#pragma unroll
        for (int t = 0; t < 2; ++t) {
#pragma unroll
            for (int kk = 0; kk < 2; ++kk) {
                const int pos = ((kk * 2 + khalf) ^ rsw) << 3;
                shortx8 ah[2], al[2], bh, bl;
#pragma unroll
                for (int i = 0; i < 2; ++i) {
                    int row = wm * 64 + i * 32 + l31;
                    ah[i] = *(const shortx8*)&As[t * 4096 + row * 32 + pos];
                    al[i] = *(const shortx8*)&As[8192 + t * 4096 + row * 32 + pos];
                }
                {
                    int col = wn * 32 + l31;
                    bh = *(const shortx8*)&Bs[t * 4096 + col * 32 + pos];
                    bl = *(const shortx8*)&Bs[8192 + t * 4096 + col * 32 + pos];
                }
#pragma unroll
                for (int i = 0; i < 2; ++i) {
                    acc[i] = __builtin_amdgcn_mfma_f32_32x32x16_bf16(ah[i], bh, acc[i], 0, 0, 0);
                    acc[i] = __builtin_amdgcn_mfma_f32_32x32x16_bf16(ah[i], bl, acc[i], 0, 0, 0);
                    acc[i] = __builtin_amdgcn_mfma_f32_32x32x16_bf16(al[i], bh, acc[i], 0, 0, 0);
                }
            }
        }
        __syncthreads();
    }

    // epilogue: col = lane&31, row = (reg&3)+8*(reg>>2)+4*(lane>>5) (m74/m101)
#pragma unroll
    for (int i = 0; i < 2; ++i) {
        int col = n0 + wn * 32 + l31;
#pragma unroll
        for (int r = 0; r < 16; ++r) {
            int row = m0 + wm * 64 + i * 32 + (r & 3) + 8 * (r >> 2) + 4 * khalf;
            C[(size_t)row * ldc + col] = acc[i][r];
        }
    }
}

// ---------------------------------------------------------------------------
// dt_proj GEMM (R19): BN=64, KP=64, single staging round, fused bias+softplus.
// ---------------------------------------------------------------------------
template <int BN, int KP>
__global__ __launch_bounds__(256) void gemm_bf16_sp(
    const unsigned short* __restrict__ A,
    const unsigned short* __restrict__ Bm,
    float* __restrict__ C, int ldc, const float* __restrict__ bias)
{
    constexpr int TN32 = BN / 64;
    __shared__ unsigned short As[2 * 8192];
    __shared__ unsigned short Bs[2 * BN * 64];

    const int tid = threadIdx.x;
    const int w = tid >> 6;
    const int lane = tid & 63;
    const int wm = w >> 1, wn = w & 1;
    const int m0 = blockIdx.y * 128;
    const int n0 = blockIdx.x * BN;

    const int r4 = lane >> 2;
    const int csw = (lane & 3) ^ ((r4 >> 1) & 3);
    const int gk = csw * 8;
    const int l31 = lane & 31;
    const int khalf = lane >> 5;
    const int rsw = (l31 >> 1) & 3;

    floatx16 acc[2][TN32] = {};

    for (int k0 = 0; k0 < KP; k0 += 64) {
#pragma unroll
        for (int seg = 0; seg < 2; ++seg) {
            const unsigned short* Asrc = A + seg * KP;
            const unsigned short* Bsrc = Bm + seg * KP;
#pragma unroll
            for (int t = 0; t < 2; ++t) {
#pragma unroll
                for (int jj = 0; jj < 2; ++jj) {
                    int j = w + jj * 4;
                    async_ld16(Asrc + (size_t)(m0 + j * 16 + r4) * (2 * KP) + k0 + t * 32 + gk,
                               &As[seg * 8192 + t * 4096 + j * 512]);
                }
#pragma unroll
                for (int jj = 0; jj < BN / 64; ++jj) {
                    int j = w + jj * 4;
                    async_ld16(Bsrc + (size_t)(n0 + j * 16 + r4) * (2 * KP) + k0 + t * 32 + gk,
                               &Bs[seg * BN * 64 + t * BN * 32 + j * 512]);
                }
            }
        }
        __syncthreads();

#pragma unroll
        for (int t = 0; t < 2; ++t) {
#pragma unroll
            for (int kk = 0; kk < 2; ++kk) {
                const int pos = ((kk * 2 + khalf) ^ rsw) << 3;
                shortx8 ah[2], al[2], bh[TN32], bl[TN32];
#pragma unroll
                for (int i = 0; i < 2; ++i) {
                    int row = wm * 64 + i * 32 + l31;
                    ah[i] = *(const shortx8*)&As[t * 4096 + row * 32 + pos];
                    al[i] = *(const shortx8*)&As[8192 + t * 4096 + row * 32 + pos];
                }
#pragma unroll
                for (int j = 0; j < TN32; ++j) {
                    int col = wn * (BN / 2) + j * 32 + l31;
                    bh[j] = *(const shortx8*)&Bs[t * BN * 32 + col * 32 + pos];
                    bl[j] = *(const shortx8*)&Bs[BN * 64 + t * BN * 32 + col * 32 + pos];
                }
#pragma unroll
                for (int i = 0; i < 2; ++i)
#pragma unroll
                    for (int j = 0; j < TN32; ++j) {
                        acc[i][j] = __builtin_amdgcn_mfma_f32_32x32x16_bf16(ah[i], bh[j], acc[i][j], 0, 0, 0);
                        acc[i][j] = __builtin_amdgcn_mfma_f32_32x32x16_bf16(ah[i], bl[j], acc[i][j], 0, 0, 0);
                        acc[i][j] = __builtin_amdgcn_mfma_f32_32x32x16_bf16(al[i], bh[j], acc[i][j], 0, 0, 0);
                    }
            }
        }
        __syncthreads();
    }

#pragma unroll
    for (int i = 0; i < 2; ++i) {
#pragma unroll
        for (int j = 0; j < TN32; ++j) {
            int col = n0 + wn * (BN / 2) + j * 32 + l31;
            float bz = bias[col];
#pragma unroll
            for (int r = 0; r < 16; ++r) {
                int row = m0 + wm * 64 + i * 32 + (r & 3) + 8 * (r >> 2) + 4 * khalf;
                C[(size_t)row * ldc + col] = softplusf(acc[i][j][r] + bz);
            }
        }
    }
}

// ---------------------------------------------------------------------------
// fp32 -> 2-segment split-bf16: row = [hi (K) | lo (K)], stride 2K (out_proj)
// ---------------------------------------------------------------------------
__global__ __launch_bounds__(256) void split2_kernel(
    const float* __restrict__ src, unsigned short* __restrict__ dst, int K)
{
    int i = blockIdx.x * 256 + threadIdx.x;
    int m = i / K;
    int k = i - m * K;
    float a = src[i];
    __hip_bfloat16 h = __float2bfloat16(a);
    __hip_bfloat16 l = __float2bfloat16(a - __bfloat162float(h));
    unsigned short* row = dst + (size_t)m * 2 * K;
    row[k] = *(unsigned short*)&h;
    row[K + k] = *(unsigned short*)&l;
}

// ---------------------------------------------------------------------------
// x_proj split-K partial GEMM + reduce (BK=64, R18)
// ---------------------------------------------------------------------------
__global__ __launch_bounds__(256) void xproj_splitk(
    const float* __restrict__ u, const float* __restrict__ Wx,
    float* __restrict__ Cp)
{
    __shared__ float As[64][68];     // [k][row]
    __shared__ float Bs[64][100];    // [k][row]

    const int tid = threadIdx.x;
    const int ks = blockIdx.x;
    const int m0 = blockIdx.y * 64;
    const int tx = tid & 15;
    const int ty = tid >> 4;

    float acc[4][6] = {};

    for (int k0 = ks * KC; k0 < (ks + 1) * KC; k0 += 64) {
        for (int idx = tid * 4; idx < 64 * 64; idx += 1024) {
            int row = idx >> 6, kk = idx & 63;
            float4 v = *(const float4*)&u[(size_t)(m0 + row) * DINNER + k0 + kk];
            As[kk + 0][row] = v.x;
            As[kk + 1][row] = v.y;
            As[kk + 2][row] = v.z;
            As[kk + 3][row] = v.w;
        }
        for (int idx = tid * 4; idx < 96 * 64; idx += 1024) {
            int row = idx >> 6, kk = idx & 63;
            float4 v = *(const float4*)&Wx[(size_t)row * DINNER + k0 + kk];
            Bs[kk + 0][row] = v.x;
            Bs[kk + 1][row] = v.y;
            Bs[kk + 2][row] = v.z;
            Bs[kk + 3][row] = v.w;
        }
        __syncthreads();

#pragma unroll 8
        for (int k = 0; k < 64; ++k) {
            float a[4], b[6];
#pragma unroll
            for (int i = 0; i < 4; ++i) a[i] = As[k][ty * 4 + i];
#pragma unroll
            for (int j = 0; j < 6; ++j) b[j] = Bs[k][tx * 6 + j];
#pragma unroll
            for (int i = 0; i < 4; ++i)
#pragma unroll
                for (int j = 0; j < 6; ++j) acc[i][j] = fmaf(a[i], b[j], acc[i][j]);
        }
        __syncthreads();
    }

    float* outp = Cp + ((size_t)ks * M_ROWS + m0) * 96;
#pragma unroll
    for (int i = 0; i < 4; ++i)
#pragma unroll
        for (int j = 0; j < 6; ++j)
            outp[(ty * 4 + i) * 96 + tx * 6 + j] = acc[i][j];
}

__global__ __launch_bounds__(256) void xproj_reduce(
    const float* __restrict__ Cp, float* __restrict__ xdbl)
{
    int i = blockIdx.x * 256 + threadIdx.x;
    float s = 0.f;
#pragma unroll
    for (int c = 0; c < KSPLIT; ++c)
        s += Cp[(size_t)c * M_ROWS * 96 + i];
    xdbl[i] = s;
}

// ---------------------------------------------------------------------------
// conv + silu, float4 over channels
// ---------------------------------------------------------------------------
__global__ __launch_bounds__(256) void conv_silu_v4(
    const float* __restrict__ xz, const float* __restrict__ cw,
    const float* __restrict__ cb, float* __restrict__ u)
{
    int i = blockIdx.x * 256 + threadIdx.x;      // over M_ROWS * 512
    int dq = (i & 511) << 2;
    int bl = i >> 9;
    int b = bl >> 11;
    int l = bl & 2047;

    float4 W0 = *(const float4*)&cw[(dq + 0) * 4];
    float4 W1 = *(const float4*)&cw[(dq + 1) * 4];
    float4 W2 = *(const float4*)&cw[(dq + 2) * 4];
    float4 W3 = *(const float4*)&cw[(dq + 3) * 4];
    float4 acc = *(const float4*)&cb[dq];

#pragma unroll
    for (int k = 0; k < 4; ++k) {
        int ls = l + k - 3;
        if (ls >= 0) {
            float4 v = *(const float4*)&xz[((size_t)(b << 11) + ls) * 4096 + dq];
            acc.x = fmaf(v.x, ((const float*)&W0)[k], acc.x);
            acc.y = fmaf(v.y, ((const float*)&W1)[k], acc.y);
            acc.z = fmaf(v.z, ((const float*)&W2)[k], acc.z);
            acc.w = fmaf(v.w, ((const float*)&W3)[k], acc.w);
        }
    }
    float4 r = make_float4(siluf(acc.x), siluf(acc.y), siluf(acc.z), siluf(acc.w));
    *(float4*)&u[(size_t)bl * DINNER + dq] = r;
}

// ---------------------------------------------------------------------------
// Chunked selective scan (3 passes). PASS3 fuses gate + split-bf16 y2
// (linear 2-seg layout [4096][hi 2048 | lo 2048]).
// ---------------------------------------------------------------------------
template <bool PASS3>
__global__ __launch_bounds__(256) void scan_chunk(
    const float* __restrict__ dbuf, const float* __restrict__ ubuf,
    const float* __restrict__ xdbl, const float* __restrict__ A_log,
    const float* __restrict__ Dv,
    float* __restrict__ Pbuf, float* __restrict__ Sbuf,
    const float* __restrict__ xz, unsigned short* __restrict__ y2)
{
    __shared__ float sd[16][CPB];
    __shared__ float su[16][CPB];
    __shared__ float sB[16][DSTATE];
    __shared__ float sC[16][DSTATE];

    const int tid = threadIdx.x;
    const int c    = blockIdx.x % CH;
    const int dblk = (blockIdx.x / CH) % (DINNER / CPB);
    const int b    = blockIdx.x / (CH * (DINNER / CPB));
    const int d0 = dblk * CPB;
    const int dg = tid >> 2;
    const int q  = tid & 3;
    const int d  = d0 + dg;
    const size_t base_bl = (size_t)b * L_SZ + (size_t)c * CLEN;

    float Ac[4], h[4];
    float sdl = 0.f;
#pragma unroll
    for (int j = 0; j < 4; ++j)
        Ac[j] = -fexpf(A_log[d * DSTATE + 4 * q + j]);
    const size_t psoff = (((size_t)b * CH + c) * DINNER + d0) * DSTATE + (size_t)tid * 4;
    if (PASS3) {
        float4 h0 = *(const float4*)&Sbuf[psoff];
        h[0] = h0.x; h[1] = h0.y; h[2] = h0.z; h[3] = h0.w;
    } else {
        h[0] = h[1] = h[2] = h[3] = 0.f;
    }
    const float Dd = PASS3 ? Dv[d] : 0.f;

    const int ls = tid >> 4;
    const int g4 = (tid & 15) * 4;
    const int ln = tid & 15;

    float4 r_d = *(const float4*)&dbuf[(base_bl + ls) * DINNER + d0 + g4];
    float4 r_u = *(const float4*)&ubuf[(base_bl + ls) * DINNER + d0 + g4];
    float r_B = xdbl[(base_bl + ls) * 96 + 64 + ln];
    float r_C = xdbl[(base_bl + ls) * 96 + 80 + ln];

    for (int l0 = 0; l0 < CLEN; l0 += 16) {
        __syncthreads();
        *(float4*)&sd[ls][g4] = r_d;
        *(float4*)&su[ls][g4] = r_u;
        sB[ls][ln] = r_B;
        sC[ls][ln] = r_C;
        __syncthreads();

        if (l0 + 16 < CLEN) {
            r_d = *(const float4*)&dbuf[(base_bl + l0 + 16 + ls) * DINNER + d0 + g4];
            r_u = *(const float4*)&ubuf[(base_bl + l0 + 16 + ls) * DINNER + d0 + g4];
            r_B = xdbl[(base_bl + l0 + 16 + ls) * 96 + 64 + ln];
            r_C = xdbl[(base_bl + l0 + 16 + ls) * 96 + 80 + ln];
        }

#pragma unroll
        for (int s = 0; s < 16; ++s) {
            float dl = sd[s][dg];
            float ul = su[s][dg];
            float4 Bv = *(float4*)&sB[s][4 * q];
            float dbu = dl * ul;
            float dA0 = fexpf(dl * Ac[0]);
            float dA1 = fexpf(dl * Ac[1]);
            float dA2 = fexpf(dl * Ac[2]);
            float dA3 = fexpf(dl * Ac[3]);
            h[0] = fmaf(dA0, h[0], dbu * Bv.x);
            h[1] = fmaf(dA1, h[1], dbu * Bv.y);
            h[2] = fmaf(dA2, h[2], dbu * Bv.z);
            h[3] = fmaf(dA3, h[3], dbu * Bv.w);
            if (!PASS3) {
                sdl += dl;
            } else {
                float4 Cv = *(float4*)&sC[s][4 * q];
                float y = h[0] * Cv.x + h[1] * Cv.y + h[2] * Cv.z + h[3] * Cv.w;
                y += __shfl_xor(y, 1);
                y += __shfl_xor(y, 2);
                if (q == 0) su[s][dg] = fmaf(ul, Dd, y);
            }
        }

        if (PASS3) {
            __syncthreads();
            size_t row = base_bl + l0 + ls;
            float4 yv = *(float4*)&su[ls][g4];
            float4 rv = *(const float4*)&xz[row * 4096 + 2048 + d0 + g4];
            float a0 = yv.x * siluf(rv.x);
            float a1 = yv.y * siluf(rv.y);
            float a2 = yv.z * siluf(rv.z);
            float a3 = yv.w * siluf(rv.w);
            __hip_bfloat16 h0 = __float2bfloat16(a0), h1 = __float2bfloat16(a1);
            __hip_bfloat16 h2 = __float2bfloat16(a2), h3 = __float2bfloat16(a3);
            __hip_bfloat16 l0b = __float2bfloat16(a0 - __bfloat162float(h0));
            __hip_bfloat16 l1b = __float2bfloat16(a1 - __bfloat162float(h1));
            __hip_bfloat16 l2b = __float2bfloat16(a2 - __bfloat162float(h2));
            __hip_bfloat16 l3b = __float2bfloat16(a3 - __bfloat162float(h3));
            ushort4 hv = make_ushort4(*(unsigned short*)&h0, *(unsigned short*)&h1,
                                      *(unsigned short*)&h2, *(unsigned short*)&h3);
            ushort4 lv = make_ushort4(*(unsigned short*)&l0b, *(unsigned short*)&l1b,
                                      *(unsigned short*)&l2b, *(unsigned short*)&l3b);
            unsigned short* yrow = y2 + row * 2 * DINNER + d0 + g4;
            *(ushort4*)&yrow[0] = hv;
            *(ushort4*)&yrow[DINNER] = lv;
        }
    }

    if (!PASS3) {
        *(float4*)&Pbuf[psoff] = make_float4(fexpf(Ac[0] * sdl), fexpf(Ac[1] * sdl),
                                             fexpf(Ac[2] * sdl), fexpf(Ac[3] * sdl));
        *(float4*)&Sbuf[psoff] = make_float4(h[0], h[1], h[2], h[3]);
    }
}

__global__ __launch_bounds__(256) void scan_combine(
    const float* __restrict__ Pbuf, float* __restrict__ Sbuf)
{
    int t = blockIdx.x * 256 + threadIdx.x;
    int b = t >> 15;
    int rem = t & 32767;
    size_t base = (size_t)b * CH * DINNER * DSTATE + rem;
    float H = 0.f;
#pragma unroll 4
    for (int c = 0; c < CH; ++c) {
        size_t off = base + (size_t)c * DINNER * DSTATE;
        float S = Sbuf[off];
        float P = Pbuf[off];
        Sbuf[off] = H;
        H = fmaf(P, H, S);
    }
}

// ---------------------------------------------------------------------------
extern "C" void kernel_launch(void* const* d_in, const int* in_sizes, int n_in,
                              void* d_out, int out_size, void* d_ws, size_t ws_size,
                              hipStream_t stream)
{
    const float* x          = (const float*)d_in[0];
    const float* in_proj_w  = (const float*)d_in[1];
    const float* conv_w     = (const float*)d_in[2];
    const float* conv_b     = (const float*)d_in[3];
    const float* x_proj_w   = (const float*)d_in[4];
    const float* dt_proj_w  = (const float*)d_in[5];
    const float* dt_proj_b  = (const float*)d_in[6];
    const float* A_log      = (const float*)d_in[7];
    const float* Dv         = (const float*)d_in[8];
    const float* out_proj_w = (const float*)d_in[9];
    float* out = (float*)d_out;

    // workspace layout (bytes):
    char* w = (char*)d_ws;
    float* xz   = (float*)(w);                       // 64 MB
    float* u    = (float*)(w + 67108864);            // 32 MB (written step 3)
    float* dbuf = (float*)(w + 100663296);           // 32 MB (written step 5)
    float* xdbl = (float*)(w + 134217728);           // 1.5 MB
    float* Pbuf = (float*)(w + 135790592);           // 8 MB (dead after combine)
    float* Sbuf = (float*)(w + 144179200);           // 8 MB (ends 152567808)
    unsigned short* y2  = (unsigned short*)(w + 152567808);   // 32 MB [4096][4096] 2-seg
    unsigned short* w2b = (unsigned short*)(w + 135790592);   // 8 MB over Pbuf (dead at 7)
    float* Cp = (float*)(w + 152567808);             // xproj partials (dead at 4, pre-y2)
    // dt_proj 2-seg inputs; over dead Cp region, consumed before pass3 writes y2
    unsigned short* dt2  = (unsigned short*)(w + 152567808);            // 1 MB
    unsigned short* wdt2 = (unsigned short*)(w + 152567808 + 1048576);  // 0.5 MB
    // dedup 2-seg panels for in_proj; ALIAS u / dbuf (dead after step 2)
    unsigned short* x2p  = (unsigned short*)(w + 67108864);   // 16 MB over u
    unsigned short* w2ap = (unsigned short*)(w + 100663296);  // 16 MB over dbuf

    // 1) split x / in_proj_w -> dedup 2-seg panels (line-read remap, 512 blk)
    split3_kernel<4096, 1024><<<512, 256, 0, stream>>>(x, x2p);
    split3_kernel<4096, 1024><<<512, 256, 0, stream>>>(in_proj_w, w2ap);
    // 2) in_proj: 8-phase GEMM, KT=48, SEGT=16, NB=16 (R16-exact, control)
    gemm_8ph<48, 16, 16, 4096><<<256, 512, 0, stream>>>(x2p, w2ap, xz);
    // 3) conv + silu -> u (overwrites x2p, dead)
    conv_silu_v4<<<(M_ROWS * 512) / 256, 256, 0, stream>>>(xz, conv_w, conv_b, u);
    // 4) x_proj via split-K (BK=64); Cp dead after reduce
    {
        dim3 g(KSPLIT, M_ROWS / 64);
        xproj_splitk<<<g, 256, 0, stream>>>(u, x_proj_w, Cp);
        xproj_reduce<<<(M_ROWS * 96) / 256, 256, 0, stream>>>(Cp, xdbl);
    }
    // 5) dt_proj on MFMA (R19): split inputs, GEMM + fused bias/softplus
    {
        split2k_kernel<96><<<1024, 256, 0, stream>>>(xdbl, dt2);
        split2k_kernel<64><<<512, 256, 0, stream>>>(dt_proj_w, wdt2);
        dim3 g(DINNER / 64, M_ROWS / 128);
        gemm_bf16_sp<64, 64><<<g, 256, 0, stream>>>(dt2, wdt2, dbuf, DINNER, dt_proj_b);
    }
    // 6) chunked selective scan; pass3 fuses gate + linear 2-seg split into y2
    {
        const int nblk = B_SZ * (DINNER / CPB) * CH;
        scan_chunk<false><<<nblk, 256, 0, stream>>>(dbuf, u, xdbl, A_log, Dv, Pbuf, Sbuf, nullptr, nullptr);
        scan_combine<<<B_SZ * DINNER * DSTATE / 256, 256, 0, stream>>>(Pbuf, Sbuf);
        scan_chunk<true><<<nblk, 256, 0, stream>>>(dbuf, u, xdbl, A_log, Dv, nullptr, Sbuf, xz, y2);
    }
    // 7) split out_proj_w (2-seg linear; Pbuf dead after combine)
    split2_kernel<<<(DMODEL * DINNER) / 256, 256, 0, stream>>>(out_proj_w, w2b, DINNER);
    // 8) out_proj via 128x128-tile 512-thread MFMA GEMM (2 waves/SIMD)
    {
        dim3 g(DMODEL / 128, M_ROWS / 128);
        gemm_bf16_128x128<2048><<<g, 512, 0, stream>>>(y2, w2b, out, 1024);
    }
}